// Round 1
// baseline (4281.233 us; speedup 1.0000x reference)
//
#include <hip/hip_runtime.h>
#include <hip/hip_bf16.h>
#include <stdint.h>

// Problem constants (from setup_inputs)
#define N_TOK 8192
#define C_DIM 2048
#define E_NUM 8
#define H_DIM 1408
#define HS_DIM 2816
#define NRPAD 17408      // 16384 routed slots + per-expert padding to 128
#define MAXTILES 136     // sum ceil(ne/128) <= 128 + 7

typedef unsigned short u16;
typedef float f32x4_t __attribute__((ext_vector_type(4)));
typedef short bf16x8_t __attribute__((ext_vector_type(8)));

__device__ __forceinline__ u16 f2bf(float f) {
  union { float f; uint32_t u; } c; c.f = f;
  uint32_t u = c.u;
  return (u16)((u + 0x7fffu + ((u >> 16) & 1u)) >> 16);
}

// ---------------- fp32 -> bf16 conversion (x only) ----------------
__global__ __launch_bounds__(256) void cvt_bf16_kernel(
    const float* __restrict__ in, u16* __restrict__ out, int n4) {
  int i = blockIdx.x * blockDim.x + threadIdx.x;
  int stride = gridDim.x * blockDim.x;
  for (; i < n4; i += stride) {
    float4 v = ((const float4*)in)[i];
    ushort4 u;
    u.x = f2bf(v.x); u.y = f2bf(v.y); u.z = f2bf(v.z); u.w = f2bf(v.w);
    ((ushort4*)out)[i] = u;
  }
}

// ---------------- gate: fp32 scores, top-2, renorm weights ----------------
__global__ __launch_bounds__(256) void gate_topk_kernel(
    const float* __restrict__ x, const float* __restrict__ gw,
    const float* __restrict__ gbias,
    int* __restrict__ tok_e, float* __restrict__ tok_w, int* __restrict__ counts) {
  int n = blockIdx.x;
  const float* xr = x + (size_t)n * C_DIM;
  int t = threadIdx.x;
  float acc[E_NUM];
#pragma unroll
  for (int e = 0; e < E_NUM; ++e) acc[e] = 0.f;
  for (int k0 = t * 4; k0 < C_DIM; k0 += 1024) {
    float4 xv = *(const float4*)(xr + k0);
#pragma unroll
    for (int e = 0; e < E_NUM; ++e) {
      float4 gv = *(const float4*)(gw + e * C_DIM + k0);
      acc[e] += xv.x * gv.x + xv.y * gv.y + xv.z * gv.z + xv.w * gv.w;
    }
  }
#pragma unroll
  for (int e = 0; e < E_NUM; ++e)
    for (int off = 32; off > 0; off >>= 1) acc[e] += __shfl_xor(acc[e], off, 64);
  __shared__ float sred[4][E_NUM];
  int wid = t >> 6, lane = t & 63;
  if (lane == 0) {
#pragma unroll
    for (int e = 0; e < E_NUM; ++e) sred[wid][e] = acc[e];
  }
  __syncthreads();
  if (t == 0) {
    float sc[E_NUM];
#pragma unroll
    for (int e = 0; e < E_NUM; ++e) {
      float s = sred[0][e] + sred[1][e] + sred[2][e] + sred[3][e];
      sc[e] = 1.f / (1.f + expf(-s));
    }
    // top-2 on (score + bias), ties -> lower index (strict >)
    int e0 = 0; float k0v = sc[0] + gbias[0];
    for (int e = 1; e < E_NUM; ++e) {
      float ke = sc[e] + gbias[e];
      if (ke > k0v) { k0v = ke; e0 = e; }
    }
    int e1 = -1; float k1v = -1e30f;
    for (int e = 0; e < E_NUM; ++e) {
      if (e == e0) continue;
      float ke = sc[e] + gbias[e];
      if (ke > k1v) { k1v = ke; e1 = e; }
    }
    float w0 = sc[e0], w1 = sc[e1];
    float s = w0 + w1;
    w0 /= s; w1 /= s;  // ROUTE_SCALE == 1.0
    tok_e[2 * n] = e0; tok_e[2 * n + 1] = e1;
    tok_w[2 * n] = w0; tok_w[2 * n + 1] = w1;
    atomicAdd(&counts[e0], 1);
    atomicAdd(&counts[e1], 1);
  }
}

// ---------------- routing scan: padded offsets + tile table ----------------
__global__ void scan_route_kernel(const int* __restrict__ counts,
                                  int* __restrict__ off_pad,
                                  int* __restrict__ tile_e, int* __restrict__ tile_s0,
                                  int* __restrict__ ntiles) {
  if (threadIdx.x == 0 && blockIdx.x == 0) {
    int off = 0, t = 0;
    for (int e = 0; e < E_NUM; ++e) {
      off_pad[e] = off;
      int tiles = (counts[e] + 127) >> 7;
      for (int i = 0; i < tiles; ++i) { tile_e[t] = e; tile_s0[t] = off + i * 128; ++t; }
      off += tiles * 128;
    }
    *ntiles = t;
  }
}

__global__ __launch_bounds__(256) void build_slots_kernel(
    const int* __restrict__ tok_e, const float* __restrict__ tok_w,
    const int* __restrict__ off_pad, int* __restrict__ cursor,
    int* __restrict__ slot_tok, float* __restrict__ slot_w) {
  int n = blockIdx.x * blockDim.x + threadIdx.x;
  if (n >= N_TOK) return;
#pragma unroll
  for (int j = 0; j < 2; ++j) {
    int e = tok_e[2 * n + j];
    int pos = atomicAdd(&cursor[e], 1);
    int s = off_pad[e] + pos;
    slot_tok[s] = n;
    slot_w[s] = tok_w[2 * n + j];
  }
}

// ---------------- fused up-proj + SwiGLU GEMM ----------------
// h[row, col] = silu( A@B[sil_base+col]^T ) * ( A@B[mul_base+col]^T ), bf16 out.
// A is bf16 [*,K]; B is fp32 [rows,K] (converted to bf16 during staging).
template <bool GATHER>
__global__ __launch_bounds__(256) void gemm_up_swiglu(
    const u16* __restrict__ Abf, const float* __restrict__ Bw,
    u16* __restrict__ Hout,
    const int* __restrict__ tile_e, const int* __restrict__ tile_s0,
    const int* __restrict__ ntiles, const int* __restrict__ slot_tok,
    int K, int ld_h, int sil_base, int mul_base, long estride) {
  int bx = blockIdx.x;
  if (GATHER) { if (bx >= *ntiles) return; }
  int slot0 = GATHER ? tile_s0[bx] : bx * 128;
  const float* Bbase = Bw;
  if (GATHER) Bbase += (size_t)tile_e[bx] * (size_t)estride;
  int n0 = blockIdx.y * 128;

  __shared__ u16 sA[128 * 64];
  __shared__ u16 sBs[128 * 64];
  __shared__ u16 sBu[128 * 64];

  int t = threadIdx.x;
  // A staging: 8 lanes per row (16B each), 32 row-groups, 4 iters
  int ag = t & 7, arb = t >> 3;
  size_t aoff[4];
#pragma unroll
  for (int it = 0; it < 4; ++it) {
    int r = arb + 32 * it;
    int rowid;
    if (GATHER) rowid = slot_tok[slot0 + r]; else rowid = slot0 + r;
    aoff[it] = (size_t)rowid * K + ag * 8;
  }
  // B staging: 16 lanes per row (float4 each), 16 row-groups, 8 iters
  int bq = t & 15, brb = t >> 4;
  int bg = bq >> 1, bh = bq & 1;

  int wid = t >> 6, lane = t & 63;
  int wm = wid >> 1, wn = wid & 1;
  int fr = lane & 15, kq = lane >> 4;

  f32x4_t zero4 = {0.f, 0.f, 0.f, 0.f};
  f32x4_t accg[4][4], accu[4][4];
#pragma unroll
  for (int m = 0; m < 4; ++m)
#pragma unroll
    for (int n = 0; n < 4; ++n) { accg[m][n] = zero4; accu[m][n] = zero4; }

  int KT = K >> 6;
  for (int kt = 0; kt < KT; ++kt) {
    int k0 = kt << 6;
    __syncthreads();
#pragma unroll
    for (int it = 0; it < 4; ++it) {
      int r = arb + 32 * it;
      uint4 v = *(const uint4*)(Abf + aoff[it] + k0);
      *(uint4*)&sA[r * 64 + (ag ^ (r & 7)) * 8] = v;
    }
#pragma unroll
    for (int it = 0; it < 8; ++it) {
      int r = brb + 16 * it;
      int pg = bg ^ (r & 7);
      const float* ps = Bbase + (size_t)(sil_base + n0 + r) * K + (k0 + bq * 4);
      float4 v = *(const float4*)ps;
      ushort4 us; us.x = f2bf(v.x); us.y = f2bf(v.y); us.z = f2bf(v.z); us.w = f2bf(v.w);
      *(ushort4*)&sBs[r * 64 + pg * 8 + bh * 4] = us;
      const float* pu = Bbase + (size_t)(mul_base + n0 + r) * K + (k0 + bq * 4);
      float4 v2 = *(const float4*)pu;
      ushort4 uu; uu.x = f2bf(v2.x); uu.y = f2bf(v2.y); uu.z = f2bf(v2.z); uu.w = f2bf(v2.w);
      *(ushort4*)&sBu[r * 64 + pg * 8 + bh * 4] = uu;
    }
    __syncthreads();
#pragma unroll
    for (int ks = 0; ks < 2; ++ks) {
      int g = ks * 4 + kq;
      bf16x8_t a[4], vbs[4], vbu[4];
#pragma unroll
      for (int m = 0; m < 4; ++m) {
        int row = wm * 64 + m * 16 + fr;
        a[m] = *(const bf16x8_t*)&sA[row * 64 + (g ^ (row & 7)) * 8];
      }
#pragma unroll
      for (int n = 0; n < 4; ++n) {
        int row = wn * 64 + n * 16 + fr;
        int idx = row * 64 + (g ^ (row & 7)) * 8;
        vbs[n] = *(const bf16x8_t*)&sBs[idx];
        vbu[n] = *(const bf16x8_t*)&sBu[idx];
      }
#pragma unroll
      for (int m = 0; m < 4; ++m)
#pragma unroll
        for (int n = 0; n < 4; ++n) {
          accg[m][n] = __builtin_amdgcn_mfma_f32_16x16x32_bf16(a[m], vbs[n], accg[m][n], 0, 0, 0);
          accu[m][n] = __builtin_amdgcn_mfma_f32_16x16x32_bf16(a[m], vbu[n], accu[m][n], 0, 0, 0);
        }
    }
  }
  // epilogue: h = silu(g) * u  (D layout: row = kq*4+reg, col = fr)
#pragma unroll
  for (int m = 0; m < 4; ++m) {
    int rbase = wm * 64 + m * 16 + kq * 4;
#pragma unroll
    for (int rr = 0; rr < 4; ++rr) {
      size_t orow = (size_t)(slot0 + rbase + rr) * ld_h;
#pragma unroll
      for (int n = 0; n < 4; ++n) {
        int col = n0 + wn * 64 + n * 16 + fr;
        float gg = accg[m][n][rr];
        float uu = accu[m][n][rr];
        float hv = (gg / (1.f + __expf(-gg))) * uu;
        Hout[orow + col] = f2bf(hv);
      }
    }
  }
}

// ---------------- down-proj GEMM ----------------
// ROUTED: out[tok[slot], col] += acc * w[slot] (atomic).  else: out[row,col] = acc.
template <bool ROUTED>
__global__ __launch_bounds__(256) void gemm_down(
    const u16* __restrict__ Hbf, const float* __restrict__ Bw,
    float* __restrict__ Out,
    const int* __restrict__ tile_e, const int* __restrict__ tile_s0,
    const int* __restrict__ ntiles,
    const int* __restrict__ slot_tok, const float* __restrict__ slot_w,
    int K, long estride) {
  int bx = blockIdx.x;
  if (ROUTED) { if (bx >= *ntiles) return; }
  int slot0 = ROUTED ? tile_s0[bx] : bx * 128;
  const float* Bbase = Bw;
  if (ROUTED) Bbase += (size_t)tile_e[bx] * (size_t)estride;
  int n0 = blockIdx.y * 128;

  __shared__ u16 sA[128 * 64];
  __shared__ u16 sB[128 * 64];

  int t = threadIdx.x;
  int ag = t & 7, arb = t >> 3;
  int bq = t & 15, brb = t >> 4;
  int bg = bq >> 1, bh = bq & 1;
  int wid = t >> 6, lane = t & 63;
  int wm = wid >> 1, wn = wid & 1;
  int fr = lane & 15, kq = lane >> 4;

  f32x4_t zero4 = {0.f, 0.f, 0.f, 0.f};
  f32x4_t acc[4][4];
#pragma unroll
  for (int m = 0; m < 4; ++m)
#pragma unroll
    for (int n = 0; n < 4; ++n) acc[m][n] = zero4;

  int KT = K >> 6;
  for (int kt = 0; kt < KT; ++kt) {
    int k0 = kt << 6;
    __syncthreads();
#pragma unroll
    for (int it = 0; it < 4; ++it) {
      int r = arb + 32 * it;
      uint4 v = *(const uint4*)(Hbf + (size_t)(slot0 + r) * K + ag * 8 + k0);
      *(uint4*)&sA[r * 64 + (ag ^ (r & 7)) * 8] = v;
    }
#pragma unroll
    for (int it = 0; it < 8; ++it) {
      int r = brb + 16 * it;
      int pg = bg ^ (r & 7);
      const float* ps = Bbase + (size_t)(n0 + r) * K + (k0 + bq * 4);
      float4 v = *(const float4*)ps;
      ushort4 us; us.x = f2bf(v.x); us.y = f2bf(v.y); us.z = f2bf(v.z); us.w = f2bf(v.w);
      *(ushort4*)&sB[r * 64 + pg * 8 + bh * 4] = us;
    }
    __syncthreads();
#pragma unroll
    for (int ks = 0; ks < 2; ++ks) {
      int g = ks * 4 + kq;
      bf16x8_t a[4], b[4];
#pragma unroll
      for (int m = 0; m < 4; ++m) {
        int row = wm * 64 + m * 16 + fr;
        a[m] = *(const bf16x8_t*)&sA[row * 64 + (g ^ (row & 7)) * 8];
      }
#pragma unroll
      for (int n = 0; n < 4; ++n) {
        int row = wn * 64 + n * 16 + fr;
        b[n] = *(const bf16x8_t*)&sB[row * 64 + (g ^ (row & 7)) * 8];
      }
#pragma unroll
      for (int m = 0; m < 4; ++m)
#pragma unroll
        for (int n = 0; n < 4; ++n)
          acc[m][n] = __builtin_amdgcn_mfma_f32_16x16x32_bf16(a[m], b[n], acc[m][n], 0, 0, 0);
    }
  }
#pragma unroll
  for (int m = 0; m < 4; ++m) {
    int rbase = wm * 64 + m * 16 + kq * 4;
#pragma unroll
    for (int rr = 0; rr < 4; ++rr) {
      int rowt = rbase + rr;
      if (ROUTED) {
        int slot = slot0 + rowt;
        int tok = slot_tok[slot];
        float w = slot_w[slot];
        float* orow = Out + (size_t)tok * C_DIM;
#pragma unroll
        for (int n = 0; n < 4; ++n) {
          int col = n0 + wn * 64 + n * 16 + fr;
          atomicAdd(&orow[col], acc[m][n][rr] * w);
        }
      } else {
        float* orow = Out + (size_t)(slot0 + rowt) * C_DIM;
#pragma unroll
        for (int n = 0; n < 4; ++n) {
          int col = n0 + wn * 64 + n * 16 + fr;
          orow[col] = acc[m][n][rr];
        }
      }
    }
  }
}

// ---------------- host launch ----------------
extern "C" void kernel_launch(void* const* d_in, const int* in_sizes, int n_in,
                              void* d_out, int out_size, void* d_ws, size_t ws_size,
                              hipStream_t stream) {
  const float* x   = (const float*)d_in[0];
  const float* gw  = (const float*)d_in[1];
  const float* gb  = (const float*)d_in[2];
  const float* sgw = (const float*)d_in[3];
  const float* sdw = (const float*)d_in[4];
  const float* upw = (const float*)d_in[5];
  const float* dww = (const float*)d_in[6];
  float* out = (float*)d_out;

  char* ws = (char*)d_ws;
  size_t off = 0;
  auto take = [&](size_t bytes) -> void* {
    size_t o = (off + 255) & ~(size_t)255;
    off = o + bytes;
    return (void*)(ws + o);
  };

  u16*   x_bf     = (u16*)take((size_t)N_TOK * C_DIM * 2);
  u16*   h_sh     = (u16*)take((size_t)N_TOK * HS_DIM * 2);
  u16*   h_rt     = (u16*)take((size_t)NRPAD * H_DIM * 2);
  int*   tok_e    = (int*)take((size_t)N_TOK * 2 * 4);
  float* tok_w    = (float*)take((size_t)N_TOK * 2 * 4);
  int*   slot_tok = (int*)take((size_t)NRPAD * 4);
  float* slot_w   = (float*)take((size_t)NRPAD * 4);
  int*   counts   = (int*)take(E_NUM * 4);
  int*   cursor   = (int*)take(E_NUM * 4);
  int*   off_pad  = (int*)take(E_NUM * 4);
  int*   ntiles   = (int*)take(4);
  int*   tile_e   = (int*)take(MAXTILES * 4);
  int*   tile_s0  = (int*)take(MAXTILES * 4);
  (void)ws_size; (void)in_sizes; (void)n_in; (void)out_size;

  // zero slot arrays + counts + cursor (contiguous span)
  size_t z0 = (size_t)((char*)slot_tok - ws);
  size_t z1 = (size_t)((char*)cursor - ws) + E_NUM * 4;
  hipMemsetAsync(ws + z0, 0, z1 - z0, stream);

  cvt_bf16_kernel<<<4096, 256, 0, stream>>>(x, x_bf, N_TOK * C_DIM / 4);
  gate_topk_kernel<<<N_TOK, 256, 0, stream>>>(x, gw, gb, tok_e, tok_w, counts);
  scan_route_kernel<<<1, 64, 0, stream>>>(counts, off_pad, tile_e, tile_s0, ntiles);
  build_slots_kernel<<<32, 256, 0, stream>>>(tok_e, tok_w, off_pad, cursor, slot_tok, slot_w);

  // shared up: chunk order y (mul) then g (silu) -> sil_base=HS, mul_base=0
  gemm_up_swiglu<false><<<dim3(64, HS_DIM / 128), 256, 0, stream>>>(
      x_bf, sgw, h_sh, nullptr, nullptr, nullptr, nullptr,
      C_DIM, HS_DIM, HS_DIM, 0, 0);
  // routed up: chunk order g (silu) then u (mul) -> sil_base=0, mul_base=H
  gemm_up_swiglu<true><<<dim3(MAXTILES, H_DIM / 128), 256, 0, stream>>>(
      x_bf, upw, h_rt, tile_e, tile_s0, ntiles, slot_tok,
      C_DIM, H_DIM, 0, H_DIM, (long)(2 * H_DIM) * C_DIM);

  // shared down: plain store (covers every output element)
  gemm_down<false><<<dim3(64, C_DIM / 128), 256, 0, stream>>>(
      h_sh, sdw, out, nullptr, nullptr, nullptr, nullptr, nullptr,
      HS_DIM, 0);
  // routed down: atomic scatter-add scaled by combine weight
  gemm_down<true><<<dim3(MAXTILES, C_DIM / 128), 256, 0, stream>>>(
      h_rt, dww, out, tile_e, tile_s0, ntiles, slot_tok, slot_w,
      H_DIM, (long)C_DIM * H_DIM);
}

// Round 2
// 1573.391 us; speedup vs baseline: 2.7210x; 2.7210x over previous
//
#include <hip/hip_runtime.h>
#include <hip/hip_bf16.h>
#include <stdint.h>

// Problem constants (from setup_inputs)
#define N_TOK 8192
#define C_DIM 2048
#define E_NUM 8
#define H_DIM 1408
#define HS_DIM 2816
#define NRPAD 17408      // 16384 routed slots + per-expert padding to 128
#define MAXTILES 136

typedef unsigned short u16;
typedef float f32x4_t __attribute__((ext_vector_type(4)));
typedef short bf16x8_t __attribute__((ext_vector_type(8)));

__device__ __forceinline__ u16 f2bf(float f) {
  union { float f; uint32_t u; } c; c.f = f;
  uint32_t u = c.u;
  return (u16)((u + 0x7fffu + ((u >> 16) & 1u)) >> 16);
}
__device__ __forceinline__ float bf2f(u16 b) {
  union { uint32_t u; float f; } c; c.u = ((uint32_t)b) << 16;
  return c.f;
}

__device__ __forceinline__ void async_copy16(const u16* gsrc, u16* ldst) {
  __builtin_amdgcn_global_load_lds(
      (const __attribute__((address_space(1))) void*)gsrc,
      (__attribute__((address_space(3))) void*)ldst, 16, 0, 0);
}

// ---------------- fp32 -> bf16 conversion ----------------
__global__ __launch_bounds__(256) void cvt_bf16_kernel(
    const float* __restrict__ in, u16* __restrict__ out, int n4) {
  int i = blockIdx.x * blockDim.x + threadIdx.x;
  int stride = gridDim.x * blockDim.x;
  for (; i < n4; i += stride) {
    float4 v = ((const float4*)in)[i];
    ushort4 u;
    u.x = f2bf(v.x); u.y = f2bf(v.y); u.z = f2bf(v.z); u.w = f2bf(v.w);
    ((ushort4*)out)[i] = u;
  }
}

// ---------------- gate: fp32 scores, top-2, renorm weights ----------------
__global__ __launch_bounds__(256) void gate_topk_kernel(
    const float* __restrict__ x, const float* __restrict__ gw,
    const float* __restrict__ gbias,
    int* __restrict__ tok_e, float* __restrict__ tok_w, int* __restrict__ counts) {
  int n = blockIdx.x;
  const float* xr = x + (size_t)n * C_DIM;
  int t = threadIdx.x;
  float acc[E_NUM];
#pragma unroll
  for (int e = 0; e < E_NUM; ++e) acc[e] = 0.f;
  for (int k0 = t * 4; k0 < C_DIM; k0 += 1024) {
    float4 xv = *(const float4*)(xr + k0);
#pragma unroll
    for (int e = 0; e < E_NUM; ++e) {
      float4 gv = *(const float4*)(gw + e * C_DIM + k0);
      acc[e] += xv.x * gv.x + xv.y * gv.y + xv.z * gv.z + xv.w * gv.w;
    }
  }
#pragma unroll
  for (int e = 0; e < E_NUM; ++e)
    for (int off = 32; off > 0; off >>= 1) acc[e] += __shfl_xor(acc[e], off, 64);
  __shared__ float sred[4][E_NUM];
  int wid = t >> 6, lane = t & 63;
  if (lane == 0) {
#pragma unroll
    for (int e = 0; e < E_NUM; ++e) sred[wid][e] = acc[e];
  }
  __syncthreads();
  if (t == 0) {
    float sc[E_NUM];
#pragma unroll
    for (int e = 0; e < E_NUM; ++e) {
      float s = sred[0][e] + sred[1][e] + sred[2][e] + sred[3][e];
      sc[e] = 1.f / (1.f + expf(-s));
    }
    int e0 = 0; float k0v = sc[0] + gbias[0];
    for (int e = 1; e < E_NUM; ++e) {
      float ke = sc[e] + gbias[e];
      if (ke > k0v) { k0v = ke; e0 = e; }
    }
    int e1 = -1; float k1v = -1e30f;
    for (int e = 0; e < E_NUM; ++e) {
      if (e == e0) continue;
      float ke = sc[e] + gbias[e];
      if (ke > k1v) { k1v = ke; e1 = e; }
    }
    float w0 = sc[e0], w1 = sc[e1];
    float s = w0 + w1;
    w0 /= s; w1 /= s;
    tok_e[2 * n] = e0; tok_e[2 * n + 1] = e1;
    tok_w[2 * n] = w0; tok_w[2 * n + 1] = w1;
    atomicAdd(&counts[e0], 1);
    atomicAdd(&counts[e1], 1);
  }
}

// ---------------- routing scan: padded offsets + tile table ----------------
__global__ void scan_route_kernel(const int* __restrict__ counts,
                                  int* __restrict__ off_pad,
                                  int* __restrict__ tile_e, int* __restrict__ tile_s0,
                                  int* __restrict__ ntiles, int* __restrict__ totrows) {
  if (threadIdx.x == 0 && blockIdx.x == 0) {
    int off = 0, t = 0;
    for (int e = 0; e < E_NUM; ++e) {
      off_pad[e] = off;
      int tiles = (counts[e] + 127) >> 7;
      for (int i = 0; i < tiles; ++i) { tile_e[t] = e; tile_s0[t] = off + i * 128; ++t; }
      off += tiles * 128;
    }
    *ntiles = t;
    *totrows = off;
  }
}

__global__ __launch_bounds__(256) void build_slots_kernel(
    const int* __restrict__ tok_e, const float* __restrict__ tok_w,
    const int* __restrict__ off_pad, int* __restrict__ cursor,
    int* __restrict__ slot_tok, float* __restrict__ slot_w) {
  int n = blockIdx.x * blockDim.x + threadIdx.x;
  if (n >= N_TOK) return;
#pragma unroll
  for (int j = 0; j < 2; ++j) {
    int e = tok_e[2 * n + j];
    int pos = atomicAdd(&cursor[e], 1);
    int s = off_pad[e] + pos;
    slot_tok[s] = n;
    slot_w[s] = tok_w[2 * n + j];
  }
}

// ---------------- m97-style 128x128x64 bf16 GEMM ----------------
// MODE 0: plain A, bf16 store       (shared up: out gu)
// MODE 1: gathered A, bf16 store    (routed up: out gu)
// MODE 2: plain A, f32 store        (shared down: out d_out)
// MODE 3: plain A, f32 atomic-add scaled by slot_w[slot] at row slot_tok[slot]
template <int MODE>
__global__ __launch_bounds__(256) void gemm128(
    const u16* __restrict__ A, const u16* __restrict__ B,
    void* __restrict__ Out, int ldo, int K,
    const int* __restrict__ tile_e, const int* __restrict__ tile_s0,
    const int* __restrict__ ntiles,
    const int* __restrict__ slot_tok, const float* __restrict__ slot_w,
    long estride) {
  constexpr bool ROUTED = (MODE == 1 || MODE == 3);
  int bx = blockIdx.x;
  if (ROUTED) { if (bx >= *ntiles) return; }
  const int m0 = ROUTED ? tile_s0[bx] : (bx << 7);
  const u16* Bb = B + (ROUTED ? (size_t)tile_e[bx] * (size_t)estride : 0);
  const int n0 = blockIdx.y << 7;

  __shared__ u16 sA[128 * 64];
  __shared__ u16 sB[128 * 64];

  const int t = threadIdx.x;
  const int w = t >> 6, lane = t & 63;
  const int lr = lane >> 3;   // row within 8-row group
  const int lk = lane & 7;    // 16B k-group

  // staging pointers: issue i covers rows i*32 + w*8 + lr, k bytes lk*16
  const u16* ap[4];
  const u16* bp[4];
#pragma unroll
  for (int i = 0; i < 4; ++i) {
    int r = i * 32 + w * 8 + lr;
    int arow = (MODE == 1) ? slot_tok[m0 + r] : (m0 + r);
    ap[i] = A + (size_t)arow * K + lk * 8;
    bp[i] = Bb + (size_t)(n0 + r) * K + lk * 8;
  }
  // wave-uniform LDS destinations (lane*16 appended by HW)
  u16* la[4]; u16* lb[4];
#pragma unroll
  for (int i = 0; i < 4; ++i) {
    la[i] = sA + i * 2048 + w * 512;
    lb[i] = sB + i * 2048 + w * 512;
  }

  const int wm = w >> 1, wn = w & 1;
  const int fr = lane & 15, kq = lane >> 4;

  f32x4_t zero4 = {0.f, 0.f, 0.f, 0.f};
  f32x4_t acc[4][4];
#pragma unroll
  for (int m = 0; m < 4; ++m)
#pragma unroll
    for (int n = 0; n < 4; ++n) acc[m][n] = zero4;

  const int KT = K >> 6;
  for (int kt = 0; kt < KT; ++kt) {
    __syncthreads();   // previous tile's ds_reads complete before overwrite
#pragma unroll
    for (int i = 0; i < 4; ++i) {
      async_copy16(ap[i], la[i]);
      async_copy16(bp[i], lb[i]);
      ap[i] += 64; bp[i] += 64;
    }
    __syncthreads();   // drains vmcnt(0): LDS tile ready
#pragma unroll
    for (int ks = 0; ks < 2; ++ks) {
      const int g = ks * 4 + kq;
      bf16x8_t a[4], b[4];
#pragma unroll
      for (int m = 0; m < 4; ++m)
        a[m] = *(const bf16x8_t*)&sA[(wm * 64 + m * 16 + fr) * 64 + g * 8];
#pragma unroll
      for (int n = 0; n < 4; ++n)
        b[n] = *(const bf16x8_t*)&sB[(wn * 64 + n * 16 + fr) * 64 + g * 8];
#pragma unroll
      for (int m = 0; m < 4; ++m)
#pragma unroll
        for (int n = 0; n < 4; ++n)
          acc[m][n] = __builtin_amdgcn_mfma_f32_16x16x32_bf16(a[m], b[n], acc[m][n], 0, 0, 0);
    }
  }

#pragma unroll
  for (int m = 0; m < 4; ++m) {
    const int rb = wm * 64 + m * 16 + kq * 4;
#pragma unroll
    for (int rr = 0; rr < 4; ++rr) {
      const int row = m0 + rb + rr;
      if (MODE == 0 || MODE == 1) {
        u16* orow = (u16*)Out + (size_t)row * ldo;
#pragma unroll
        for (int n = 0; n < 4; ++n) {
          int col = n0 + wn * 64 + n * 16 + fr;
          orow[col] = f2bf(acc[m][n][rr]);
        }
      } else if (MODE == 2) {
        float* orow = (float*)Out + (size_t)row * ldo;
#pragma unroll
        for (int n = 0; n < 4; ++n) {
          int col = n0 + wn * 64 + n * 16 + fr;
          orow[col] = acc[m][n][rr];
        }
      } else {
        int tok = slot_tok[row];
        float wv = slot_w[row];
        float* orow = (float*)Out + (size_t)tok * ldo;
#pragma unroll
        for (int n = 0; n < 4; ++n) {
          int col = n0 + wn * 64 + n * 16 + fr;
          atomicAdd(&orow[col], acc[m][n][rr] * wv);
        }
      }
    }
  }
}

// ---------------- SwiGLU elementwise: h = silu(gu[:,sil_off+j]) * gu[:,mul_off+j] ----------------
__global__ __launch_bounds__(256) void swiglu_kernel(
    const u16* __restrict__ gu, u16* __restrict__ h,
    int width, int sil_off, int mul_off, const int* __restrict__ rowbound) {
  int row = blockIdx.y;
  if (rowbound && row >= *rowbound) return;
  int j8 = blockIdx.x * blockDim.x + threadIdx.x;
  if (j8 * 8 >= width) return;
  const u16* base = gu + (size_t)row * 2 * width;
  union { uint4 v; u16 s[8]; } G, U, R;
  G.v = *(const uint4*)(base + sil_off + j8 * 8);
  U.v = *(const uint4*)(base + mul_off + j8 * 8);
#pragma unroll
  for (int e = 0; e < 8; ++e) {
    float g = bf2f(G.s[e]);
    float u = bf2f(U.s[e]);
    float hv = (g / (1.f + __expf(-g))) * u;
    R.s[e] = f2bf(hv);
  }
  *(uint4*)(h + (size_t)row * width + j8 * 8) = R.v;
}

// ---------------- host launch ----------------
extern "C" void kernel_launch(void* const* d_in, const int* in_sizes, int n_in,
                              void* d_out, int out_size, void* d_ws, size_t ws_size,
                              hipStream_t stream) {
  const float* x   = (const float*)d_in[0];
  const float* gw  = (const float*)d_in[1];
  const float* gb  = (const float*)d_in[2];
  const float* sgw = (const float*)d_in[3];
  const float* sdw = (const float*)d_in[4];
  const float* upw = (const float*)d_in[5];
  const float* dww = (const float*)d_in[6];
  float* out = (float*)d_out;

  char* ws = (char*)d_ws;
  size_t off = 0;
  auto take = [&](size_t bytes) -> void* {
    size_t o = (off + 255) & ~(size_t)255;
    off = o + bytes;
    return (void*)(ws + o);
  };

  u16* x_bf   = (u16*)take((size_t)N_TOK * C_DIM * 2);
  u16* sgw_bf = (u16*)take((size_t)(2 * HS_DIM) * C_DIM * 2);
  u16* sdw_bf = (u16*)take((size_t)C_DIM * HS_DIM * 2);
  u16* upw_bf = (u16*)take((size_t)E_NUM * (2 * H_DIM) * C_DIM * 2);
  u16* dww_bf = (u16*)take((size_t)E_NUM * C_DIM * H_DIM * 2);
  u16* gu     = (u16*)take((size_t)NRPAD * (2 * H_DIM) * 2);   // also covers 8192x5632
  u16* h_sh   = (u16*)take((size_t)N_TOK * HS_DIM * 2);
  u16* h_rt   = upw_bf;  // alias: upw_bf dead after routed-up GEMM; 49MB <= 92MB

  int*   tok_e    = (int*)take((size_t)N_TOK * 2 * 4);
  float* tok_w    = (float*)take((size_t)N_TOK * 2 * 4);
  int*   slot_tok = (int*)take((size_t)NRPAD * 4);
  float* slot_w   = (float*)take((size_t)NRPAD * 4);
  int*   counts   = (int*)take(E_NUM * 4);
  int*   cursor   = (int*)take(E_NUM * 4);
  int*   off_pad  = (int*)take(E_NUM * 4);
  int*   ntiles   = (int*)take(4);
  int*   totrows  = (int*)take(4);
  int*   tile_e   = (int*)take(MAXTILES * 4);
  int*   tile_s0  = (int*)take(MAXTILES * 4);
  (void)ws_size; (void)in_sizes; (void)n_in; (void)out_size;

  // zero slot arrays + counts + cursor (contiguous span)
  size_t z0 = (size_t)((char*)slot_tok - ws);
  size_t z1 = (size_t)((char*)cursor - ws) + E_NUM * 4;
  hipMemsetAsync(ws + z0, 0, z1 - z0, stream);

  // weight/activation bf16 conversion
  cvt_bf16_kernel<<<2048, 256, 0, stream>>>(x, x_bf, N_TOK * C_DIM / 4);
  cvt_bf16_kernel<<<2048, 256, 0, stream>>>(sgw, sgw_bf, 2 * HS_DIM * C_DIM / 4);
  cvt_bf16_kernel<<<2048, 256, 0, stream>>>(sdw, sdw_bf, C_DIM * HS_DIM / 4);
  cvt_bf16_kernel<<<4096, 256, 0, stream>>>(upw, upw_bf, E_NUM * 2 * H_DIM * C_DIM / 4);
  cvt_bf16_kernel<<<4096, 256, 0, stream>>>(dww, dww_bf, E_NUM * C_DIM * H_DIM / 4);

  gate_topk_kernel<<<N_TOK, 256, 0, stream>>>(x, gw, gb, tok_e, tok_w, counts);
  scan_route_kernel<<<1, 64, 0, stream>>>(counts, off_pad, tile_e, tile_s0, ntiles, totrows);
  build_slots_kernel<<<32, 256, 0, stream>>>(tok_e, tok_w, off_pad, cursor, slot_tok, slot_w);

  // shared up: gu = x @ sgw^T   [8192 x 5632]
  gemm128<0><<<dim3(64, (2 * HS_DIM) / 128), 256, 0, stream>>>(
      x_bf, sgw_bf, gu, 2 * HS_DIM, C_DIM,
      nullptr, nullptr, nullptr, nullptr, nullptr, 0);
  // shared swiglu: y first, g second -> sil_off=HS, mul_off=0
  swiglu_kernel<<<dim3(2, N_TOK), 256, 0, stream>>>(gu, h_sh, HS_DIM, HS_DIM, 0, nullptr);

  // routed up: gu = gather(x) @ upw[e]^T   [slots x 2816]
  gemm128<1><<<dim3(MAXTILES, (2 * H_DIM) / 128), 256, 0, stream>>>(
      x_bf, upw_bf, gu, 2 * H_DIM, C_DIM,
      tile_e, tile_s0, ntiles, slot_tok, nullptr, (long)(2 * H_DIM) * C_DIM);
  // routed swiglu: g first, u second -> sil_off=0, mul_off=H
  swiglu_kernel<<<dim3(1, NRPAD), 256, 0, stream>>>(gu, h_rt, H_DIM, 0, H_DIM, totrows);

  // shared down: out = h_sh @ sdw^T (plain store, covers all elements)
  gemm128<2><<<dim3(64, C_DIM / 128), 256, 0, stream>>>(
      h_sh, sdw_bf, out, C_DIM, HS_DIM,
      nullptr, nullptr, nullptr, nullptr, nullptr, 0);
  // routed down: out[tok] += w * (h_rt @ dww[e]^T)
  gemm128<3><<<dim3(MAXTILES, C_DIM / 128), 256, 0, stream>>>(
      h_rt, dww_bf, out, C_DIM, H_DIM,
      tile_e, tile_s0, ntiles, slot_tok, slot_w, (long)C_DIM * H_DIM);
}

// Round 3
// 1458.182 us; speedup vs baseline: 2.9360x; 1.0790x over previous
//
#include <hip/hip_runtime.h>
#include <hip/hip_bf16.h>
#include <stdint.h>

// Problem constants (from setup_inputs)
#define N_TOK 8192
#define C_DIM 2048
#define E_NUM 8
#define H_DIM 1408
#define HS_DIM 2816
#define NRPAD 17408      // 16384 routed slots + per-expert padding to 128
#define MAXTILES 136

typedef unsigned short u16;
typedef float f32x4_t __attribute__((ext_vector_type(4)));
typedef short bf16x8_t __attribute__((ext_vector_type(8)));

__device__ __forceinline__ u16 f2bf(float f) {
  union { float f; uint32_t u; } c; c.f = f;
  uint32_t u = c.u;
  return (u16)((u + 0x7fffu + ((u >> 16) & 1u)) >> 16);
}
__device__ __forceinline__ float bf2f(u16 b) {
  union { uint32_t u; float f; } c; c.u = ((uint32_t)b) << 16;
  return c.f;
}

__device__ __forceinline__ void async_copy16(const u16* gsrc, u16* ldst) {
  __builtin_amdgcn_global_load_lds(
      (const __attribute__((address_space(1))) void*)gsrc,
      (__attribute__((address_space(3))) void*)ldst, 16, 0, 0);
}

// ---------------- fp32 -> bf16 conversion ----------------
__global__ __launch_bounds__(256) void cvt_bf16_kernel(
    const float* __restrict__ in, u16* __restrict__ out, int n4) {
  int i = blockIdx.x * blockDim.x + threadIdx.x;
  int stride = gridDim.x * blockDim.x;
  for (; i < n4; i += stride) {
    float4 v = ((const float4*)in)[i];
    ushort4 u;
    u.x = f2bf(v.x); u.y = f2bf(v.y); u.z = f2bf(v.z); u.w = f2bf(v.w);
    ((ushort4*)out)[i] = u;
  }
}

// ---------------- gate: fp32 scores, top-2, renorm weights ----------------
__global__ __launch_bounds__(256) void gate_topk_kernel(
    const float* __restrict__ x, const float* __restrict__ gw,
    const float* __restrict__ gbias,
    int* __restrict__ tok_e, float* __restrict__ tok_w, int* __restrict__ counts) {
  int n = blockIdx.x;
  const float* xr = x + (size_t)n * C_DIM;
  int t = threadIdx.x;
  float acc[E_NUM];
#pragma unroll
  for (int e = 0; e < E_NUM; ++e) acc[e] = 0.f;
  for (int k0 = t * 4; k0 < C_DIM; k0 += 1024) {
    float4 xv = *(const float4*)(xr + k0);
#pragma unroll
    for (int e = 0; e < E_NUM; ++e) {
      float4 gv = *(const float4*)(gw + e * C_DIM + k0);
      acc[e] += xv.x * gv.x + xv.y * gv.y + xv.z * gv.z + xv.w * gv.w;
    }
  }
#pragma unroll
  for (int e = 0; e < E_NUM; ++e)
    for (int off = 32; off > 0; off >>= 1) acc[e] += __shfl_xor(acc[e], off, 64);
  __shared__ float sred[4][E_NUM];
  int wid = t >> 6, lane = t & 63;
  if (lane == 0) {
#pragma unroll
    for (int e = 0; e < E_NUM; ++e) sred[wid][e] = acc[e];
  }
  __syncthreads();
  if (t == 0) {
    float sc[E_NUM];
#pragma unroll
    for (int e = 0; e < E_NUM; ++e) {
      float s = sred[0][e] + sred[1][e] + sred[2][e] + sred[3][e];
      sc[e] = 1.f / (1.f + expf(-s));
    }
    int e0 = 0; float k0v = sc[0] + gbias[0];
    for (int e = 1; e < E_NUM; ++e) {
      float ke = sc[e] + gbias[e];
      if (ke > k0v) { k0v = ke; e0 = e; }
    }
    int e1 = -1; float k1v = -1e30f;
    for (int e = 0; e < E_NUM; ++e) {
      if (e == e0) continue;
      float ke = sc[e] + gbias[e];
      if (ke > k1v) { k1v = ke; e1 = e; }
    }
    float w0 = sc[e0], w1 = sc[e1];
    float s = w0 + w1;
    w0 /= s; w1 /= s;
    tok_e[2 * n] = e0; tok_e[2 * n + 1] = e1;
    tok_w[2 * n] = w0; tok_w[2 * n + 1] = w1;
    atomicAdd(&counts[e0], 1);
    atomicAdd(&counts[e1], 1);
  }
}

// ---------------- routing scan: padded offsets + tile table ----------------
__global__ void scan_route_kernel(const int* __restrict__ counts,
                                  int* __restrict__ off_pad,
                                  int* __restrict__ tile_e, int* __restrict__ tile_s0,
                                  int* __restrict__ ntiles, int* __restrict__ totrows) {
  if (threadIdx.x == 0 && blockIdx.x == 0) {
    int off = 0, t = 0;
    for (int e = 0; e < E_NUM; ++e) {
      off_pad[e] = off;
      int tiles = (counts[e] + 127) >> 7;
      for (int i = 0; i < tiles; ++i) { tile_e[t] = e; tile_s0[t] = off + i * 128; ++t; }
      off += tiles * 128;
    }
    *ntiles = t;
    *totrows = off;
  }
}

__global__ __launch_bounds__(256) void build_slots_kernel(
    const int* __restrict__ tok_e, const int* __restrict__ off_pad,
    int* __restrict__ cursor, int* __restrict__ slot_tok, int* __restrict__ slot_of) {
  int n = blockIdx.x * blockDim.x + threadIdx.x;
  if (n >= N_TOK) return;
#pragma unroll
  for (int j = 0; j < 2; ++j) {
    int e = tok_e[2 * n + j];
    int pos = atomicAdd(&cursor[e], 1);
    int s = off_pad[e] + pos;
    slot_tok[s] = n;
    slot_of[2 * n + j] = s;
  }
}

// ---------------- m97-style 128x128x64 bf16 GEMM ----------------
// GATHER: A rows indirected via slot_tok. ROUTE: B base selected by tile_e,
// m-tiles from tile table. F32OUT: f32 plain store (else bf16 store).
template <bool GATHER, bool ROUTE, bool F32OUT>
__global__ __launch_bounds__(256) void gemm128(
    const u16* __restrict__ A, const u16* __restrict__ B,
    void* __restrict__ Out, int ldo, int K, int nbm,
    const int* __restrict__ tile_e, const int* __restrict__ tile_s0,
    const int* __restrict__ ntiles, const int* __restrict__ slot_tok,
    long estride) {
  // T1: XCD-aware bijective swizzle (gridDim.x % 8 == 0 by construction)
  const int chunk = gridDim.x >> 3;
  const int orig = blockIdx.x;
  const int wg = (orig & 7) * chunk + (orig >> 3);
  const int mt = wg % nbm;
  const int nt = wg / nbm;
  if (ROUTE) { if (mt >= *ntiles) return; }
  const int m0 = ROUTE ? tile_s0[mt] : (mt << 7);
  const u16* Bb = B + (ROUTE ? (size_t)tile_e[mt] * (size_t)estride : 0);
  const int n0 = nt << 7;

  __shared__ u16 sA[128 * 64];
  __shared__ u16 sB[128 * 64];

  const int t = threadIdx.x;
  const int w = t >> 6, lane = t & 63;
  const int lr = lane >> 3;   // row within 8-row group
  const int lk = lane & 7;    // 16B k-group

  const u16* ap[4];
  const u16* bp[4];
#pragma unroll
  for (int i = 0; i < 4; ++i) {
    int r = i * 32 + w * 8 + lr;
    int arow = GATHER ? slot_tok[m0 + r] : (m0 + r);
    ap[i] = A + (size_t)arow * K + lk * 8;
    bp[i] = Bb + (size_t)(n0 + r) * K + lk * 8;
  }
  u16* la[4]; u16* lb[4];
#pragma unroll
  for (int i = 0; i < 4; ++i) {
    la[i] = sA + i * 2048 + w * 512;
    lb[i] = sB + i * 2048 + w * 512;
  }

  const int wm = w >> 1, wn = w & 1;
  const int fr = lane & 15, kq = lane >> 4;

  f32x4_t zero4 = {0.f, 0.f, 0.f, 0.f};
  f32x4_t acc[4][4];
#pragma unroll
  for (int m = 0; m < 4; ++m)
#pragma unroll
    for (int n = 0; n < 4; ++n) acc[m][n] = zero4;

  const int KT = K >> 6;
  for (int kt = 0; kt < KT; ++kt) {
    __syncthreads();   // previous tile's ds_reads complete before overwrite
#pragma unroll
    for (int i = 0; i < 4; ++i) {
      async_copy16(ap[i], la[i]);
      async_copy16(bp[i], lb[i]);
      ap[i] += 64; bp[i] += 64;
    }
    __syncthreads();   // drains vmcnt(0): LDS tile ready
#pragma unroll
    for (int ks = 0; ks < 2; ++ks) {
      const int g = ks * 4 + kq;
      bf16x8_t a[4], b[4];
#pragma unroll
      for (int m = 0; m < 4; ++m)
        a[m] = *(const bf16x8_t*)&sA[(wm * 64 + m * 16 + fr) * 64 + g * 8];
#pragma unroll
      for (int n = 0; n < 4; ++n)
        b[n] = *(const bf16x8_t*)&sB[(wn * 64 + n * 16 + fr) * 64 + g * 8];
#pragma unroll
      for (int m = 0; m < 4; ++m)
#pragma unroll
        for (int n = 0; n < 4; ++n)
          acc[m][n] = __builtin_amdgcn_mfma_f32_16x16x32_bf16(a[m], b[n], acc[m][n], 0, 0, 0);
    }
  }

#pragma unroll
  for (int m = 0; m < 4; ++m) {
    const int rb = wm * 64 + m * 16 + kq * 4;
#pragma unroll
    for (int rr = 0; rr < 4; ++rr) {
      const int row = m0 + rb + rr;
      if (F32OUT) {
        float* orow = (float*)Out + (size_t)row * ldo;
#pragma unroll
        for (int n = 0; n < 4; ++n) {
          int col = n0 + wn * 64 + n * 16 + fr;
          orow[col] = acc[m][n][rr];
        }
      } else {
        u16* orow = (u16*)Out + (size_t)row * ldo;
#pragma unroll
        for (int n = 0; n < 4; ++n) {
          int col = n0 + wn * 64 + n * 16 + fr;
          orow[col] = f2bf(acc[m][n][rr]);
        }
      }
    }
  }
}

// ---------------- SwiGLU elementwise ----------------
__global__ __launch_bounds__(256) void swiglu_kernel(
    const u16* __restrict__ gu, u16* __restrict__ h,
    int width, int sil_off, int mul_off, const int* __restrict__ rowbound) {
  int row = blockIdx.y;
  if (rowbound && row >= *rowbound) return;
  int j8 = blockIdx.x * blockDim.x + threadIdx.x;
  if (j8 * 8 >= width) return;
  const u16* base = gu + (size_t)row * 2 * width;
  union { uint4 v; u16 s[8]; } G, U, R;
  G.v = *(const uint4*)(base + sil_off + j8 * 8);
  U.v = *(const uint4*)(base + mul_off + j8 * 8);
#pragma unroll
  for (int e = 0; e < 8; ++e) {
    float g = bf2f(G.s[e]);
    float u = bf2f(U.s[e]);
    float hv = (g / (1.f + __expf(-g))) * u;
    R.s[e] = f2bf(hv);
  }
  *(uint4*)(h + (size_t)row * width + j8 * 8) = R.v;
}

// ---------------- combine: out[tok] += w0*p[slot0] + w1*p[slot1] ----------------
__global__ __launch_bounds__(256) void combine_kernel(
    float* __restrict__ out, const u16* __restrict__ p_rt,
    const int* __restrict__ slot_of, const float* __restrict__ tok_w) {
  int tok = blockIdx.x;
  int j = threadIdx.x;               // 256 threads x 8 cols = 2048
  int s0 = slot_of[2 * tok], s1 = slot_of[2 * tok + 1];
  float w0 = tok_w[2 * tok], w1 = tok_w[2 * tok + 1];
  const u16* r0 = p_rt + (size_t)s0 * C_DIM + j * 8;
  const u16* r1 = p_rt + (size_t)s1 * C_DIM + j * 8;
  float* o = out + (size_t)tok * C_DIM + j * 8;
  union { uint4 v; u16 s[8]; } P0, P1;
  P0.v = *(const uint4*)r0;
  P1.v = *(const uint4*)r1;
  float4 o0 = *(const float4*)o;
  float4 o1 = *(const float4*)(o + 4);
  float r[8];
#pragma unroll
  for (int e = 0; e < 8; ++e) r[e] = w0 * bf2f(P0.s[e]) + w1 * bf2f(P1.s[e]);
  o0.x += r[0]; o0.y += r[1]; o0.z += r[2]; o0.w += r[3];
  o1.x += r[4]; o1.y += r[5]; o1.z += r[6]; o1.w += r[7];
  *(float4*)o = o0;
  *(float4*)(o + 4) = o1;
}

// ---------------- host launch ----------------
extern "C" void kernel_launch(void* const* d_in, const int* in_sizes, int n_in,
                              void* d_out, int out_size, void* d_ws, size_t ws_size,
                              hipStream_t stream) {
  const float* x   = (const float*)d_in[0];
  const float* gw  = (const float*)d_in[1];
  const float* gb  = (const float*)d_in[2];
  const float* sgw = (const float*)d_in[3];
  const float* sdw = (const float*)d_in[4];
  const float* upw = (const float*)d_in[5];
  const float* dww = (const float*)d_in[6];
  float* out = (float*)d_out;

  char* ws = (char*)d_ws;
  size_t off = 0;
  auto take = [&](size_t bytes) -> void* {
    size_t o = (off + 255) & ~(size_t)255;
    off = o + bytes;
    return (void*)(ws + o);
  };

  u16* x_bf   = (u16*)take((size_t)N_TOK * C_DIM * 2);
  u16* sgw_bf = (u16*)take((size_t)(2 * HS_DIM) * C_DIM * 2);
  u16* sdw_bf = (u16*)take((size_t)C_DIM * HS_DIM * 2);
  u16* upw_bf = (u16*)take((size_t)E_NUM * (2 * H_DIM) * C_DIM * 2);
  u16* dww_bf = (u16*)take((size_t)E_NUM * C_DIM * H_DIM * 2);
  u16* gu     = (u16*)take((size_t)NRPAD * (2 * H_DIM) * 2);   // also covers 8192x5632
  u16* h_sh   = (u16*)take((size_t)N_TOK * HS_DIM * 2);
  u16* h_rt   = upw_bf;  // alias: upw_bf dead after routed-up GEMM (49MB <= 92MB)
  u16* p_rt   = gu;      // alias: gu dead after routed swiglu (71MB <= 98MB)

  int*   tok_e    = (int*)take((size_t)N_TOK * 2 * 4);
  float* tok_w    = (float*)take((size_t)N_TOK * 2 * 4);
  int*   slot_of  = (int*)take((size_t)N_TOK * 2 * 4);
  int*   slot_tok = (int*)take((size_t)NRPAD * 4);      // zeroed span start
  int*   counts   = (int*)take(E_NUM * 4);
  int*   cursor   = (int*)take(E_NUM * 4);
  int*   off_pad  = (int*)take(E_NUM * 4);
  int*   ntiles   = (int*)take(4);
  int*   totrows  = (int*)take(4);
  int*   tile_e   = (int*)take(MAXTILES * 4);
  int*   tile_s0  = (int*)take(MAXTILES * 4);
  (void)ws_size; (void)in_sizes; (void)n_in; (void)out_size;

  // zero slot_tok + counts + cursor (contiguous span)
  size_t z0 = (size_t)((char*)slot_tok - ws);
  size_t z1 = (size_t)((char*)cursor - ws) + E_NUM * 4;
  hipMemsetAsync(ws + z0, 0, z1 - z0, stream);

  // weight/activation bf16 conversion
  cvt_bf16_kernel<<<2048, 256, 0, stream>>>(x, x_bf, N_TOK * C_DIM / 4);
  cvt_bf16_kernel<<<2048, 256, 0, stream>>>(sgw, sgw_bf, 2 * HS_DIM * C_DIM / 4);
  cvt_bf16_kernel<<<2048, 256, 0, stream>>>(sdw, sdw_bf, C_DIM * HS_DIM / 4);
  cvt_bf16_kernel<<<4096, 256, 0, stream>>>(upw, upw_bf, E_NUM * 2 * H_DIM * C_DIM / 4);
  cvt_bf16_kernel<<<4096, 256, 0, stream>>>(dww, dww_bf, E_NUM * C_DIM * H_DIM / 4);

  gate_topk_kernel<<<N_TOK, 256, 0, stream>>>(x, gw, gb, tok_e, tok_w, counts);
  scan_route_kernel<<<1, 64, 0, stream>>>(counts, off_pad, tile_e, tile_s0, ntiles, totrows);
  build_slots_kernel<<<32, 256, 0, stream>>>(tok_e, off_pad, cursor, slot_tok, slot_of);

  // shared up: gu = x @ sgw^T   [8192 x 5632]; grid 64 x 44 = 2816 (%8==0)
  gemm128<false, false, false><<<64 * ((2 * HS_DIM) / 128), 256, 0, stream>>>(
      x_bf, sgw_bf, gu, 2 * HS_DIM, C_DIM, 64,
      nullptr, nullptr, nullptr, nullptr, 0);
  // shared swiglu: y first, g second -> sil_off=HS, mul_off=0
  swiglu_kernel<<<dim3(2, N_TOK), 256, 0, stream>>>(gu, h_sh, HS_DIM, HS_DIM, 0, nullptr);

  // routed up: gu = gather(x) @ upw[e]^T; grid 136 x 22 = 2992 (%8==0)
  gemm128<true, true, false><<<MAXTILES * ((2 * H_DIM) / 128), 256, 0, stream>>>(
      x_bf, upw_bf, gu, 2 * H_DIM, C_DIM, MAXTILES,
      tile_e, tile_s0, ntiles, slot_tok, (long)(2 * H_DIM) * C_DIM);
  // routed swiglu: g first, u second -> sil_off=0, mul_off=H
  swiglu_kernel<<<dim3(1, NRPAD), 256, 0, stream>>>(gu, h_rt, H_DIM, 0, H_DIM, totrows);

  // shared down: out = h_sh @ sdw^T (f32 store); grid 64 x 16 = 1024 (%8==0)
  gemm128<false, false, true><<<64 * (C_DIM / 128), 256, 0, stream>>>(
      h_sh, sdw_bf, out, C_DIM, HS_DIM, 64,
      nullptr, nullptr, nullptr, nullptr, 0);
  // routed down: p_rt[slot] = h_rt[slot] @ dww[e]^T (bf16); grid 136 x 16 = 2176 (%8==0)
  gemm128<false, true, false><<<MAXTILES * (C_DIM / 128), 256, 0, stream>>>(
      h_rt, dww_bf, p_rt, C_DIM, H_DIM, MAXTILES,
      tile_e, tile_s0, ntiles, nullptr, (long)C_DIM * H_DIM);

  // combine: out[tok] += w0*p_rt[slot0] + w1*p_rt[slot1]
  combine_kernel<<<N_TOK, 256, 0, stream>>>(out, p_rt, slot_of, tok_w);
}

// Round 4
// 1410.135 us; speedup vs baseline: 3.0360x; 1.0341x over previous
//
#include <hip/hip_runtime.h>
#include <hip/hip_bf16.h>
#include <stdint.h>

// Problem constants (from setup_inputs)
#define N_TOK 8192
#define C_DIM 2048
#define E_NUM 8
#define H_DIM 1408
#define HS_DIM 2816
#define NRPAD 17408      // 16384 routed slots + per-expert padding to 128
#define MAXTILES 136

typedef unsigned short u16;
typedef float f32x4_t __attribute__((ext_vector_type(4)));
typedef short bf16x8_t __attribute__((ext_vector_type(8)));

__device__ __forceinline__ u16 f2bf(float f) {
  union { float f; uint32_t u; } c; c.f = f;
  uint32_t u = c.u;
  return (u16)((u + 0x7fffu + ((u >> 16) & 1u)) >> 16);
}
__device__ __forceinline__ float bf2f(u16 b) {
  union { uint32_t u; float f; } c; c.u = ((uint32_t)b) << 16;
  return c.f;
}

__device__ __forceinline__ void async_copy16(const u16* gsrc, u16* ldst) {
  __builtin_amdgcn_global_load_lds(
      (const __attribute__((address_space(1))) void*)gsrc,
      (__attribute__((address_space(3))) void*)ldst, 16, 0, 0);
}

// ---------------- fp32 -> bf16 conversion ----------------
__global__ __launch_bounds__(256) void cvt_bf16_kernel(
    const float* __restrict__ in, u16* __restrict__ out, int n4) {
  int i = blockIdx.x * blockDim.x + threadIdx.x;
  int stride = gridDim.x * blockDim.x;
  for (; i < n4; i += stride) {
    float4 v = ((const float4*)in)[i];
    ushort4 u;
    u.x = f2bf(v.x); u.y = f2bf(v.y); u.z = f2bf(v.z); u.w = f2bf(v.w);
    ((ushort4*)out)[i] = u;
  }
}

// ---------------- gate: fp32 scores, top-2, renorm weights ----------------
__global__ __launch_bounds__(256) void gate_topk_kernel(
    const float* __restrict__ x, const float* __restrict__ gw,
    const float* __restrict__ gbias,
    int* __restrict__ tok_e, float* __restrict__ tok_w, int* __restrict__ counts) {
  int n = blockIdx.x;
  const float* xr = x + (size_t)n * C_DIM;
  int t = threadIdx.x;
  float acc[E_NUM];
#pragma unroll
  for (int e = 0; e < E_NUM; ++e) acc[e] = 0.f;
  for (int k0 = t * 4; k0 < C_DIM; k0 += 1024) {
    float4 xv = *(const float4*)(xr + k0);
#pragma unroll
    for (int e = 0; e < E_NUM; ++e) {
      float4 gv = *(const float4*)(gw + e * C_DIM + k0);
      acc[e] += xv.x * gv.x + xv.y * gv.y + xv.z * gv.z + xv.w * gv.w;
    }
  }
#pragma unroll
  for (int e = 0; e < E_NUM; ++e)
    for (int off = 32; off > 0; off >>= 1) acc[e] += __shfl_xor(acc[e], off, 64);
  __shared__ float sred[4][E_NUM];
  int wid = t >> 6, lane = t & 63;
  if (lane == 0) {
#pragma unroll
    for (int e = 0; e < E_NUM; ++e) sred[wid][e] = acc[e];
  }
  __syncthreads();
  if (t == 0) {
    float sc[E_NUM];
#pragma unroll
    for (int e = 0; e < E_NUM; ++e) {
      float s = sred[0][e] + sred[1][e] + sred[2][e] + sred[3][e];
      sc[e] = 1.f / (1.f + expf(-s));
    }
    int e0 = 0; float k0v = sc[0] + gbias[0];
    for (int e = 1; e < E_NUM; ++e) {
      float ke = sc[e] + gbias[e];
      if (ke > k0v) { k0v = ke; e0 = e; }
    }
    int e1 = -1; float k1v = -1e30f;
    for (int e = 0; e < E_NUM; ++e) {
      if (e == e0) continue;
      float ke = sc[e] + gbias[e];
      if (ke > k1v) { k1v = ke; e1 = e; }
    }
    float w0 = sc[e0], w1 = sc[e1];
    float s = w0 + w1;
    w0 /= s; w1 /= s;
    tok_e[2 * n] = e0; tok_e[2 * n + 1] = e1;
    tok_w[2 * n] = w0; tok_w[2 * n + 1] = w1;
    atomicAdd(&counts[e0], 1);
    atomicAdd(&counts[e1], 1);
  }
}

// ---------------- routing scan: padded offsets + tile table ----------------
__global__ void scan_route_kernel(const int* __restrict__ counts,
                                  int* __restrict__ off_pad,
                                  int* __restrict__ tile_e, int* __restrict__ tile_s0,
                                  int* __restrict__ ntiles, int* __restrict__ totrows) {
  if (threadIdx.x == 0 && blockIdx.x == 0) {
    int off = 0, t = 0;
    for (int e = 0; e < E_NUM; ++e) {
      off_pad[e] = off;
      int tiles = (counts[e] + 127) >> 7;
      for (int i = 0; i < tiles; ++i) { tile_e[t] = e; tile_s0[t] = off + i * 128; ++t; }
      off += tiles * 128;
    }
    *ntiles = t;
    *totrows = off;
  }
}

__global__ __launch_bounds__(256) void build_slots_kernel(
    const int* __restrict__ tok_e, const int* __restrict__ off_pad,
    int* __restrict__ cursor, int* __restrict__ slot_tok, int* __restrict__ slot_of) {
  int n = blockIdx.x * blockDim.x + threadIdx.x;
  if (n >= N_TOK) return;
#pragma unroll
  for (int j = 0; j < 2; ++j) {
    int e = tok_e[2 * n + j];
    int pos = atomicAdd(&cursor[e], 1);
    int s = off_pad[e] + pos;
    slot_tok[s] = n;
    slot_of[2 * n + j] = s;
  }
}

// ---------------- m97-style 128x128x64 bf16 GEMM ----------------
// GATHER: A rows indirected via slot_tok. ROUTE: B base selected by tile_e,
// m-tiles from tile table. F32OUT: f32 plain store (else bf16 store).
// Tile mapping: XCD-contiguous chunks; within a chunk, 8-mt-tall bands swept
// across nt -> co-resident window ~8mt x 8nt (A band L2-resident, B streams).
template <bool GATHER, bool ROUTE, bool F32OUT>
__global__ __launch_bounds__(256) void gemm128(
    const u16* __restrict__ A, const u16* __restrict__ B,
    void* __restrict__ Out, int ldo, int K, int nbn,
    const int* __restrict__ tile_e, const int* __restrict__ tile_s0,
    const int* __restrict__ ntiles, const int* __restrict__ slot_tok,
    long estride) {
  const int chunk = gridDim.x >> 3;
  const int orig = blockIdx.x;
  const int l = (orig & 7) * chunk + (orig >> 3);   // contiguous within XCD
  const int bandsz = nbn << 3;
  const int band = l / bandsz;
  const int rem = l - band * bandsz;
  const int nt = rem >> 3;
  const int mt = (band << 3) + (rem & 7);
  if (ROUTE) { if (mt >= *ntiles) return; }
  const int m0 = ROUTE ? tile_s0[mt] : (mt << 7);
  const u16* Bb = B + (ROUTE ? (size_t)tile_e[mt] * (size_t)estride : 0);
  const int n0 = nt << 7;

  __shared__ u16 sA[128 * 64];
  __shared__ u16 sB[128 * 64];

  const int t = threadIdx.x;
  const int w = t >> 6, lane = t & 63;
  const int lr = lane >> 3;   // row within 8-row group
  const int lk = lane & 7;    // 16B k-group

  const u16* ap[4];
  const u16* bp[4];
#pragma unroll
  for (int i = 0; i < 4; ++i) {
    int r = i * 32 + w * 8 + lr;
    int arow = GATHER ? slot_tok[m0 + r] : (m0 + r);
    ap[i] = A + (size_t)arow * K + lk * 8;
    bp[i] = Bb + (size_t)(n0 + r) * K + lk * 8;
  }
  u16* la[4]; u16* lb[4];
#pragma unroll
  for (int i = 0; i < 4; ++i) {
    la[i] = sA + i * 2048 + w * 512;
    lb[i] = sB + i * 2048 + w * 512;
  }

  const int wm = w >> 1, wn = w & 1;
  const int fr = lane & 15, kq = lane >> 4;

  f32x4_t zero4 = {0.f, 0.f, 0.f, 0.f};
  f32x4_t acc[4][4];
#pragma unroll
  for (int m = 0; m < 4; ++m)
#pragma unroll
    for (int n = 0; n < 4; ++n) acc[m][n] = zero4;

  const int KT = K >> 6;
  for (int kt = 0; kt < KT; ++kt) {
    __syncthreads();   // previous tile's ds_reads complete before overwrite
#pragma unroll
    for (int i = 0; i < 4; ++i) {
      async_copy16(ap[i], la[i]);
      async_copy16(bp[i], lb[i]);
      ap[i] += 64; bp[i] += 64;
    }
    __syncthreads();   // drains vmcnt(0): LDS tile ready
#pragma unroll
    for (int ks = 0; ks < 2; ++ks) {
      const int g = ks * 4 + kq;
      bf16x8_t a[4], b[4];
#pragma unroll
      for (int m = 0; m < 4; ++m)
        a[m] = *(const bf16x8_t*)&sA[(wm * 64 + m * 16 + fr) * 64 + g * 8];
#pragma unroll
      for (int n = 0; n < 4; ++n)
        b[n] = *(const bf16x8_t*)&sB[(wn * 64 + n * 16 + fr) * 64 + g * 8];
#pragma unroll
      for (int m = 0; m < 4; ++m)
#pragma unroll
        for (int n = 0; n < 4; ++n)
          acc[m][n] = __builtin_amdgcn_mfma_f32_16x16x32_bf16(a[m], b[n], acc[m][n], 0, 0, 0);
    }
  }

#pragma unroll
  for (int m = 0; m < 4; ++m) {
    const int rb = wm * 64 + m * 16 + kq * 4;
#pragma unroll
    for (int rr = 0; rr < 4; ++rr) {
      const int row = m0 + rb + rr;
      if (F32OUT) {
        float* orow = (float*)Out + (size_t)row * ldo;
#pragma unroll
        for (int n = 0; n < 4; ++n) {
          int col = n0 + wn * 64 + n * 16 + fr;
          orow[col] = acc[m][n][rr];
        }
      } else {
        u16* orow = (u16*)Out + (size_t)row * ldo;
#pragma unroll
        for (int n = 0; n < 4; ++n) {
          int col = n0 + wn * 64 + n * 16 + fr;
          orow[col] = f2bf(acc[m][n][rr]);
        }
      }
    }
  }
}

// ---------------- SwiGLU elementwise ----------------
__global__ __launch_bounds__(256) void swiglu_kernel(
    const u16* __restrict__ gu, u16* __restrict__ h,
    int width, int sil_off, int mul_off, const int* __restrict__ rowbound) {
  int row = blockIdx.y;
  if (rowbound && row >= *rowbound) return;
  int j8 = blockIdx.x * blockDim.x + threadIdx.x;
  if (j8 * 8 >= width) return;
  const u16* base = gu + (size_t)row * 2 * width;
  union { uint4 v; u16 s[8]; } G, U, R;
  G.v = *(const uint4*)(base + sil_off + j8 * 8);
  U.v = *(const uint4*)(base + mul_off + j8 * 8);
#pragma unroll
  for (int e = 0; e < 8; ++e) {
    float g = bf2f(G.s[e]);
    float u = bf2f(U.s[e]);
    float hv = (g / (1.f + __expf(-g))) * u;
    R.s[e] = f2bf(hv);
  }
  *(uint4*)(h + (size_t)row * width + j8 * 8) = R.v;
}

// ---------------- combine: out[tok] += w0*p[slot0] + w1*p[slot1] ----------------
__global__ __launch_bounds__(256) void combine_kernel(
    float* __restrict__ out, const u16* __restrict__ p_rt,
    const int* __restrict__ slot_of, const float* __restrict__ tok_w) {
  int tok = blockIdx.x;
  int j = threadIdx.x;               // 256 threads x 8 cols = 2048
  int s0 = slot_of[2 * tok], s1 = slot_of[2 * tok + 1];
  float w0 = tok_w[2 * tok], w1 = tok_w[2 * tok + 1];
  const u16* r0 = p_rt + (size_t)s0 * C_DIM + j * 8;
  const u16* r1 = p_rt + (size_t)s1 * C_DIM + j * 8;
  float* o = out + (size_t)tok * C_DIM + j * 8;
  union { uint4 v; u16 s[8]; } P0, P1;
  P0.v = *(const uint4*)r0;
  P1.v = *(const uint4*)r1;
  float4 o0 = *(const float4*)o;
  float4 o1 = *(const float4*)(o + 4);
  float r[8];
#pragma unroll
  for (int e = 0; e < 8; ++e) r[e] = w0 * bf2f(P0.s[e]) + w1 * bf2f(P1.s[e]);
  o0.x += r[0]; o0.y += r[1]; o0.z += r[2]; o0.w += r[3];
  o1.x += r[4]; o1.y += r[5]; o1.z += r[6]; o1.w += r[7];
  *(float4*)o = o0;
  *(float4*)(o + 4) = o1;
}

// ---------------- host launch ----------------
extern "C" void kernel_launch(void* const* d_in, const int* in_sizes, int n_in,
                              void* d_out, int out_size, void* d_ws, size_t ws_size,
                              hipStream_t stream) {
  const float* x   = (const float*)d_in[0];
  const float* gw  = (const float*)d_in[1];
  const float* gb  = (const float*)d_in[2];
  const float* sgw = (const float*)d_in[3];
  const float* sdw = (const float*)d_in[4];
  const float* upw = (const float*)d_in[5];
  const float* dww = (const float*)d_in[6];
  float* out = (float*)d_out;

  char* ws = (char*)d_ws;
  size_t off = 0;
  auto take = [&](size_t bytes) -> void* {
    size_t o = (off + 255) & ~(size_t)255;
    off = o + bytes;
    return (void*)(ws + o);
  };

  u16* x_bf   = (u16*)take((size_t)N_TOK * C_DIM * 2);
  u16* sgw_bf = (u16*)take((size_t)(2 * HS_DIM) * C_DIM * 2);
  u16* sdw_bf = (u16*)take((size_t)C_DIM * HS_DIM * 2);
  u16* upw_bf = (u16*)take((size_t)E_NUM * (2 * H_DIM) * C_DIM * 2);
  u16* dww_bf = (u16*)take((size_t)E_NUM * C_DIM * H_DIM * 2);
  u16* gu     = (u16*)take((size_t)NRPAD * (2 * H_DIM) * 2);   // also covers 8192x5632
  u16* h_sh   = (u16*)take((size_t)N_TOK * HS_DIM * 2);
  u16* h_rt   = upw_bf;  // alias: upw_bf dead after routed-up GEMM (49MB <= 92MB)
  u16* p_rt   = gu;      // alias: gu dead after routed swiglu (71MB <= 98MB)

  int*   tok_e    = (int*)take((size_t)N_TOK * 2 * 4);
  float* tok_w    = (float*)take((size_t)N_TOK * 2 * 4);
  int*   slot_of  = (int*)take((size_t)N_TOK * 2 * 4);
  int*   slot_tok = (int*)take((size_t)NRPAD * 4);      // zeroed span start
  int*   counts   = (int*)take(E_NUM * 4);
  int*   cursor   = (int*)take(E_NUM * 4);
  int*   off_pad  = (int*)take(E_NUM * 4);
  int*   ntiles   = (int*)take(4);
  int*   totrows  = (int*)take(4);
  int*   tile_e   = (int*)take(MAXTILES * 4);
  int*   tile_s0  = (int*)take(MAXTILES * 4);
  (void)ws_size; (void)in_sizes; (void)n_in; (void)out_size;

  // zero slot_tok + counts + cursor (contiguous span)
  size_t z0 = (size_t)((char*)slot_tok - ws);
  size_t z1 = (size_t)((char*)cursor - ws) + E_NUM * 4;
  hipMemsetAsync(ws + z0, 0, z1 - z0, stream);

  // weight/activation bf16 conversion
  cvt_bf16_kernel<<<2048, 256, 0, stream>>>(x, x_bf, N_TOK * C_DIM / 4);
  cvt_bf16_kernel<<<2048, 256, 0, stream>>>(sgw, sgw_bf, 2 * HS_DIM * C_DIM / 4);
  cvt_bf16_kernel<<<2048, 256, 0, stream>>>(sdw, sdw_bf, C_DIM * HS_DIM / 4);
  cvt_bf16_kernel<<<4096, 256, 0, stream>>>(upw, upw_bf, E_NUM * 2 * H_DIM * C_DIM / 4);
  cvt_bf16_kernel<<<4096, 256, 0, stream>>>(dww, dww_bf, E_NUM * C_DIM * H_DIM / 4);

  gate_topk_kernel<<<N_TOK, 256, 0, stream>>>(x, gw, gb, tok_e, tok_w, counts);
  scan_route_kernel<<<1, 64, 0, stream>>>(counts, off_pad, tile_e, tile_s0, ntiles, totrows);
  build_slots_kernel<<<32, 256, 0, stream>>>(tok_e, off_pad, cursor, slot_tok, slot_of);

  // shared up: gu = x @ sgw^T   [8192 x 5632]; 64 mt x 44 nt
  gemm128<false, false, false><<<64 * ((2 * HS_DIM) / 128), 256, 0, stream>>>(
      x_bf, sgw_bf, gu, 2 * HS_DIM, C_DIM, (2 * HS_DIM) / 128,
      nullptr, nullptr, nullptr, nullptr, 0);
  // shared swiglu: y first, g second -> sil_off=HS, mul_off=0
  swiglu_kernel<<<dim3(2, N_TOK), 256, 0, stream>>>(gu, h_sh, HS_DIM, HS_DIM, 0, nullptr);

  // routed up: gu = gather(x) @ upw[e]^T; 136 mt x 22 nt
  gemm128<true, true, false><<<MAXTILES * ((2 * H_DIM) / 128), 256, 0, stream>>>(
      x_bf, upw_bf, gu, 2 * H_DIM, C_DIM, (2 * H_DIM) / 128,
      tile_e, tile_s0, ntiles, slot_tok, (long)(2 * H_DIM) * C_DIM);
  // routed swiglu: g first, u second -> sil_off=0, mul_off=H
  swiglu_kernel<<<dim3(1, NRPAD), 256, 0, stream>>>(gu, h_rt, H_DIM, 0, H_DIM, totrows);

  // shared down: out = h_sh @ sdw^T (f32 store); 64 mt x 16 nt
  gemm128<false, false, true><<<64 * (C_DIM / 128), 256, 0, stream>>>(
      h_sh, sdw_bf, out, C_DIM, HS_DIM, C_DIM / 128,
      nullptr, nullptr, nullptr, nullptr, 0);
  // routed down: p_rt[slot] = h_rt[slot] @ dww[e]^T (bf16); 136 mt x 16 nt
  gemm128<false, true, false><<<MAXTILES * (C_DIM / 128), 256, 0, stream>>>(
      h_rt, dww_bf, p_rt, C_DIM, H_DIM, C_DIM / 128,
      tile_e, tile_s0, ntiles, nullptr, (long)C_DIM * H_DIM);

  // combine: out[tok] += w0*p_rt[slot0] + w1*p_rt[slot1]
  combine_kernel<<<N_TOK, 256, 0, stream>>>(out, p_rt, slot_of, tok_w);
}

// Round 5
// 1109.769 us; speedup vs baseline: 3.8578x; 1.2707x over previous
//
#include <hip/hip_runtime.h>
#include <hip/hip_bf16.h>
#include <stdint.h>

// Problem constants (from setup_inputs)
#define N_TOK 8192
#define C_DIM 2048
#define E_NUM 8
#define H_DIM 1408
#define HS_DIM 2816
#define NRPAD 18432      // 16384 routed slots + per-expert padding to 256
#define MAXT256 72       // 64 full tiles + 8 partial

typedef unsigned short u16;
typedef float f32x4_t __attribute__((ext_vector_type(4)));
typedef short bf16x8_t __attribute__((ext_vector_type(8)));

__device__ __forceinline__ u16 f2bf(float f) {
  union { float f; uint32_t u; } c; c.f = f;
  uint32_t u = c.u;
  return (u16)((u + 0x7fffu + ((u >> 16) & 1u)) >> 16);
}
__device__ __forceinline__ float bf2f(u16 b) {
  union { uint32_t u; float f; } c; c.u = ((uint32_t)b) << 16;
  return c.f;
}

__device__ __forceinline__ void async_copy16(const u16* gsrc, u16* ldst) {
  __builtin_amdgcn_global_load_lds(
      (const __attribute__((address_space(1))) void*)gsrc,
      (__attribute__((address_space(3))) void*)ldst, 16, 0, 0);
}

#define BARRIER() asm volatile("s_barrier" ::: "memory")
#define WAITV4()  asm volatile("s_waitcnt vmcnt(4)" ::: "memory")
#define WAITV0()  asm volatile("s_waitcnt vmcnt(0)" ::: "memory")

// ---------------- fp32 -> bf16 conversion ----------------
__global__ __launch_bounds__(256) void cvt_bf16_kernel(
    const float* __restrict__ in, u16* __restrict__ out, int n4) {
  int i = blockIdx.x * blockDim.x + threadIdx.x;
  int stride = gridDim.x * blockDim.x;
  for (; i < n4; i += stride) {
    float4 v = ((const float4*)in)[i];
    ushort4 u;
    u.x = f2bf(v.x); u.y = f2bf(v.y); u.z = f2bf(v.z); u.w = f2bf(v.w);
    ((ushort4*)out)[i] = u;
  }
}

// ---------------- gate: fp32 scores, top-2, renorm weights ----------------
__global__ __launch_bounds__(256) void gate_topk_kernel(
    const float* __restrict__ x, const float* __restrict__ gw,
    const float* __restrict__ gbias,
    int* __restrict__ tok_e, float* __restrict__ tok_w, int* __restrict__ counts) {
  int n = blockIdx.x;
  const float* xr = x + (size_t)n * C_DIM;
  int t = threadIdx.x;
  float acc[E_NUM];
#pragma unroll
  for (int e = 0; e < E_NUM; ++e) acc[e] = 0.f;
  for (int k0 = t * 4; k0 < C_DIM; k0 += 1024) {
    float4 xv = *(const float4*)(xr + k0);
#pragma unroll
    for (int e = 0; e < E_NUM; ++e) {
      float4 gv = *(const float4*)(gw + e * C_DIM + k0);
      acc[e] += xv.x * gv.x + xv.y * gv.y + xv.z * gv.z + xv.w * gv.w;
    }
  }
#pragma unroll
  for (int e = 0; e < E_NUM; ++e)
    for (int off = 32; off > 0; off >>= 1) acc[e] += __shfl_xor(acc[e], off, 64);
  __shared__ float sred[4][E_NUM];
  int wid = t >> 6, lane = t & 63;
  if (lane == 0) {
#pragma unroll
    for (int e = 0; e < E_NUM; ++e) sred[wid][e] = acc[e];
  }
  __syncthreads();
  if (t == 0) {
    float sc[E_NUM];
#pragma unroll
    for (int e = 0; e < E_NUM; ++e) {
      float s = sred[0][e] + sred[1][e] + sred[2][e] + sred[3][e];
      sc[e] = 1.f / (1.f + expf(-s));
    }
    int e0 = 0; float k0v = sc[0] + gbias[0];
    for (int e = 1; e < E_NUM; ++e) {
      float ke = sc[e] + gbias[e];
      if (ke > k0v) { k0v = ke; e0 = e; }
    }
    int e1 = -1; float k1v = -1e30f;
    for (int e = 0; e < E_NUM; ++e) {
      if (e == e0) continue;
      float ke = sc[e] + gbias[e];
      if (ke > k1v) { k1v = ke; e1 = e; }
    }
    float w0 = sc[e0], w1 = sc[e1];
    float s = w0 + w1;
    w0 /= s; w1 /= s;
    tok_e[2 * n] = e0; tok_e[2 * n + 1] = e1;
    tok_w[2 * n] = w0; tok_w[2 * n + 1] = w1;
    atomicAdd(&counts[e0], 1);
    atomicAdd(&counts[e1], 1);
  }
}

// ---------------- routing scan: 256-padded offsets + tile table ----------------
__global__ void scan_route_kernel(const int* __restrict__ counts,
                                  int* __restrict__ off_pad,
                                  int* __restrict__ tile_e, int* __restrict__ tile_s0,
                                  int* __restrict__ ntiles, int* __restrict__ totrows) {
  if (threadIdx.x == 0 && blockIdx.x == 0) {
    int off = 0, t = 0;
    for (int e = 0; e < E_NUM; ++e) {
      off_pad[e] = off;
      int tiles = (counts[e] + 255) >> 8;
      for (int i = 0; i < tiles; ++i) { tile_e[t] = e; tile_s0[t] = off + i * 256; ++t; }
      off += tiles * 256;
    }
    *ntiles = t;
    *totrows = off;
  }
}

__global__ __launch_bounds__(256) void build_slots_kernel(
    const int* __restrict__ tok_e, const int* __restrict__ off_pad,
    int* __restrict__ cursor, int* __restrict__ slot_tok, int* __restrict__ slot_of) {
  int n = blockIdx.x * blockDim.x + threadIdx.x;
  if (n >= N_TOK) return;
#pragma unroll
  for (int j = 0; j < 2; ++j) {
    int e = tok_e[2 * n + j];
    int pos = atomicAdd(&cursor[e], 1);
    int s = off_pad[e] + pos;
    slot_tok[s] = n;
    slot_of[2 * n + j] = s;
  }
}

// ---------------- 256x256x64 8-phase bf16 GEMM (T2+T3+T4+T5) ----------------
// 512 threads = 8 waves (2 wm x 4 wn); per-wave output 128x64 (8x4 frags).
// LDS per buffer: A,B each [2 ks][256 r][32 k] bf16 (k-major halves so each
// half-tile is contiguous for global_load_lds). Double-buffered = 128 KiB.
// T2 swizzle: LDS col ^= (row&3)*8 elems, applied via pre-swizzled global
// source (linear LDS dest) + XOR on ds_read (rule: both-sides-or-neither).
// Schedule per K-tile: 4 phases {(qm0,ks0)(qm1,ks0)(qm0,ks1)(qm1,ks1)}, each
// stages one half-tile of the NEXT K-tile (2 loads); counted vmcnt(4) only at
// phases 2 and 4 (2 HTs in flight), never 0 in the main loop.
template <bool GATHER, bool ROUTE, bool F32OUT>
__global__ __launch_bounds__(512, 2) void gemm256(
    const u16* __restrict__ A, const u16* __restrict__ B,
    void* __restrict__ Out, int ldo, int K, int nbn,
    const int* __restrict__ tile_e, const int* __restrict__ tile_s0,
    const int* __restrict__ ntiles, const int* __restrict__ slot_tok,
    long estride) {
  // XCD-contiguous chunks; within a chunk, 4-mt bands swept across nt.
  const int chunk = gridDim.x >> 3;
  const int orig = blockIdx.x;
  const int l = (orig & 7) * chunk + (orig >> 3);
  const int bandsz = nbn << 2;
  const int band = l / bandsz;
  const int rem = l - band * bandsz;
  const int nt = rem >> 2;
  const int mt = (band << 2) + (rem & 3);
  if (ROUTE) { if (mt >= *ntiles) return; }
  const int m0 = ROUTE ? tile_s0[mt] : (mt << 8);
  const u16* Bb = B + (ROUTE ? (size_t)tile_e[mt] * (size_t)estride : 0);
  const int n0 = nt << 8;

  __shared__ u16 lds[65536];   // [buf(2)][mat(2)][ks(2)][256][32]

  const int t = threadIdx.x;
  const int w = t >> 6, lane = t & 63;
  const int wst = w << 9;                  // wave LDS slice within an issue
  // staging source pointers (pre-swizzled global col)
  const int rt2 = t >> 2;                  // 0..127
  const int coff = (((t & 3) ^ (rt2 & 3)) << 3);
  const u16* aS[2]; const u16* bS[2];
#pragma unroll
  for (int j = 0; j < 2; ++j) {
    int r = (j << 7) + rt2;
    int arow = GATHER ? slot_tok[m0 + r] : (m0 + r);
    aS[j] = A + (size_t)arow * K + coff;
    bS[j] = Bb + (size_t)(n0 + r) * K + coff;
  }

  const int wm = w >> 2, wn = w & 3;
  const int fr = lane & 15, kq = lane >> 4;
  const int swz = ((kq << 3) ^ ((fr & 3) << 3));   // u16, within 64B row

  f32x4_t acc[8][4];
  f32x4_t zero4 = {0.f, 0.f, 0.f, 0.f};
#pragma unroll
  for (int m = 0; m < 8; ++m)
#pragma unroll
    for (int n = 0; n < 4; ++n) acc[m][n] = zero4;

#define STG_A(KS) \
  async_copy16(aS[0] + kst + (KS)*32, &lds[nxtb + (KS)*8192 + wst]); \
  async_copy16(aS[1] + kst + (KS)*32, &lds[nxtb + (KS)*8192 + 4096 + wst]);
#define STG_B(KS) \
  async_copy16(bS[0] + kst + (KS)*32, &lds[nxtb + 16384 + (KS)*8192 + wst]); \
  async_copy16(bS[1] + kst + (KS)*32, &lds[nxtb + 16384 + (KS)*8192 + 4096 + wst]);
#define LDA(QM, KS) \
  _Pragma("unroll") \
  for (int m = 0; m < 4; ++m) { \
    int row = (wm << 7) + (QM)*64 + (m << 4) + fr; \
    afr[m] = *(const bf16x8_t*)&lds[cur + (KS)*8192 + (row << 5) + swz]; \
  }
#define LDB(KS) \
  _Pragma("unroll") \
  for (int n = 0; n < 4; ++n) { \
    int row = (wn << 6) + (n << 4) + fr; \
    bfr[n] = *(const bf16x8_t*)&lds[cur + 16384 + (KS)*8192 + (row << 5) + swz]; \
  }
#define MFMA16(QM) \
  __builtin_amdgcn_s_setprio(1); \
  _Pragma("unroll") \
  for (int m = 0; m < 4; ++m) \
    _Pragma("unroll") \
    for (int n = 0; n < 4; ++n) \
      acc[(QM)*4 + m][n] = __builtin_amdgcn_mfma_f32_16x16x32_bf16( \
          afr[m], bfr[n], acc[(QM)*4 + m][n], 0, 0, 0); \
  __builtin_amdgcn_s_setprio(0);

  const int KT = K >> 6;
  // prologue: stage K-tile 0 into buf0 (order A0,B0,A1,B1), wait first 2 HTs
  {
    const int nxtb = 0, kst = 0;
    STG_A(0); STG_B(0); STG_A(1); STG_B(1);
  }
  WAITV4();
  BARRIER();

  for (int kt = 0; kt < KT; ++kt) {
    const int cur = (kt & 1) << 15;
    const int nxtb = ((kt + 1) & 1) << 15;
    const int kst = (kt + 1 < KT ? kt + 1 : kt) << 6;   // last tile: junk re-stage
    bf16x8_t afr[4], bfr[4];

    // phase 1: (qm0, ks0); stage A-ks0 of next
    LDB(0); LDA(0, 0); STG_A(0);
    BARRIER();
    MFMA16(0);
    BARRIER();
    // phase 2: (qm1, ks0); stage B-ks0
    LDA(1, 0); STG_B(0);
    BARRIER();
    MFMA16(1);
    WAITV4();        // A1(kt),B1(kt) landed; A0/B0(kt+1) may fly
    BARRIER();
    // phase 3: (qm0, ks1); stage A-ks1
    LDB(1); LDA(0, 1); STG_A(1);
    BARRIER();
    MFMA16(0);
    BARRIER();
    // phase 4: (qm1, ks1); stage B-ks1
    LDA(1, 1); STG_B(1);
    BARRIER();
    MFMA16(1);
    WAITV4();        // A0(kt+1),B0(kt+1) landed; A1/B1(kt+1) may fly
    BARRIER();
  }
  WAITV0();          // drain junk stages before LDS dealloc

  // epilogue
#pragma unroll
  for (int mf = 0; mf < 8; ++mf) {
    const int rb = (wm << 7) + (mf << 4) + (kq << 2);
#pragma unroll
    for (int rr = 0; rr < 4; ++rr) {
      const int row = m0 + rb + rr;
      if (F32OUT) {
        float* orow = (float*)Out + (size_t)row * ldo;
#pragma unroll
        for (int n = 0; n < 4; ++n)
          orow[n0 + (wn << 6) + (n << 4) + fr] = acc[mf][n][rr];
      } else {
        u16* orow = (u16*)Out + (size_t)row * ldo;
#pragma unroll
        for (int n = 0; n < 4; ++n)
          orow[n0 + (wn << 6) + (n << 4) + fr] = f2bf(acc[mf][n][rr]);
      }
    }
  }
#undef STG_A
#undef STG_B
#undef LDA
#undef LDB
#undef MFMA16
}

// ---------------- SwiGLU elementwise ----------------
__global__ __launch_bounds__(256) void swiglu_kernel(
    const u16* __restrict__ gu, u16* __restrict__ h,
    int width, int sil_off, int mul_off, const int* __restrict__ rowbound) {
  int row = blockIdx.y;
  if (rowbound && row >= *rowbound) return;
  int j8 = blockIdx.x * blockDim.x + threadIdx.x;
  if (j8 * 8 >= width) return;
  const u16* base = gu + (size_t)row * 2 * width;
  union { uint4 v; u16 s[8]; } G, U, R;
  G.v = *(const uint4*)(base + sil_off + j8 * 8);
  U.v = *(const uint4*)(base + mul_off + j8 * 8);
#pragma unroll
  for (int e = 0; e < 8; ++e) {
    float g = bf2f(G.s[e]);
    float u = bf2f(U.s[e]);
    float hv = (g / (1.f + __expf(-g))) * u;
    R.s[e] = f2bf(hv);
  }
  *(uint4*)(h + (size_t)row * width + j8 * 8) = R.v;
}

// ---------------- combine: out[tok] += w0*p[slot0] + w1*p[slot1] ----------------
__global__ __launch_bounds__(256) void combine_kernel(
    float* __restrict__ out, const u16* __restrict__ p_rt,
    const int* __restrict__ slot_of, const float* __restrict__ tok_w) {
  int tok = blockIdx.x;
  int j = threadIdx.x;               // 256 threads x 8 cols = 2048
  int s0 = slot_of[2 * tok], s1 = slot_of[2 * tok + 1];
  float w0 = tok_w[2 * tok], w1 = tok_w[2 * tok + 1];
  const u16* r0 = p_rt + (size_t)s0 * C_DIM + j * 8;
  const u16* r1 = p_rt + (size_t)s1 * C_DIM + j * 8;
  float* o = out + (size_t)tok * C_DIM + j * 8;
  union { uint4 v; u16 s[8]; } P0, P1;
  P0.v = *(const uint4*)r0;
  P1.v = *(const uint4*)r1;
  float4 o0 = *(const float4*)o;
  float4 o1 = *(const float4*)(o + 4);
  float r[8];
#pragma unroll
  for (int e = 0; e < 8; ++e) r[e] = w0 * bf2f(P0.s[e]) + w1 * bf2f(P1.s[e]);
  o0.x += r[0]; o0.y += r[1]; o0.z += r[2]; o0.w += r[3];
  o1.x += r[4]; o1.y += r[5]; o1.z += r[6]; o1.w += r[7];
  *(float4*)o = o0;
  *(float4*)(o + 4) = o1;
}

// ---------------- host launch ----------------
extern "C" void kernel_launch(void* const* d_in, const int* in_sizes, int n_in,
                              void* d_out, int out_size, void* d_ws, size_t ws_size,
                              hipStream_t stream) {
  const float* x   = (const float*)d_in[0];
  const float* gw  = (const float*)d_in[1];
  const float* gb  = (const float*)d_in[2];
  const float* sgw = (const float*)d_in[3];
  const float* sdw = (const float*)d_in[4];
  const float* upw = (const float*)d_in[5];
  const float* dww = (const float*)d_in[6];
  float* out = (float*)d_out;

  char* ws = (char*)d_ws;
  size_t off = 0;
  auto take = [&](size_t bytes) -> void* {
    size_t o = (off + 255) & ~(size_t)255;
    off = o + bytes;
    return (void*)(ws + o);
  };

  u16* x_bf   = (u16*)take((size_t)N_TOK * C_DIM * 2);
  u16* sgw_bf = (u16*)take((size_t)(2 * HS_DIM) * C_DIM * 2);
  u16* sdw_bf = (u16*)take((size_t)C_DIM * HS_DIM * 2);
  u16* upw_bf = (u16*)take((size_t)E_NUM * (2 * H_DIM) * C_DIM * 2);
  u16* dww_bf = (u16*)take((size_t)E_NUM * C_DIM * H_DIM * 2);
  u16* gu     = (u16*)take((size_t)NRPAD * (2 * H_DIM) * 2);   // covers 8192x5632 too
  u16* h_sh   = (u16*)take((size_t)N_TOK * HS_DIM * 2);
  u16* h_rt   = upw_bf;  // alias: upw_bf dead after routed-up GEMM (52MB <= 92MB)
  u16* p_rt   = gu;      // alias: gu dead after routed swiglu (76MB <= 104MB)

  int*   tok_e    = (int*)take((size_t)N_TOK * 2 * 4);
  float* tok_w    = (float*)take((size_t)N_TOK * 2 * 4);
  int*   slot_of  = (int*)take((size_t)N_TOK * 2 * 4);
  int*   slot_tok = (int*)take((size_t)NRPAD * 4);      // zeroed span start
  int*   counts   = (int*)take(E_NUM * 4);
  int*   cursor   = (int*)take(E_NUM * 4);
  int*   off_pad  = (int*)take(E_NUM * 4);
  int*   ntiles   = (int*)take(4);
  int*   totrows  = (int*)take(4);
  int*   tile_e   = (int*)take(MAXT256 * 4);
  int*   tile_s0  = (int*)take(MAXT256 * 4);
  (void)ws_size; (void)in_sizes; (void)n_in; (void)out_size;

  // zero slot_tok + counts + cursor (contiguous span)
  size_t z0 = (size_t)((char*)slot_tok - ws);
  size_t z1 = (size_t)((char*)cursor - ws) + E_NUM * 4;
  hipMemsetAsync(ws + z0, 0, z1 - z0, stream);

  // weight/activation bf16 conversion
  cvt_bf16_kernel<<<2048, 256, 0, stream>>>(x, x_bf, N_TOK * C_DIM / 4);
  cvt_bf16_kernel<<<2048, 256, 0, stream>>>(sgw, sgw_bf, 2 * HS_DIM * C_DIM / 4);
  cvt_bf16_kernel<<<2048, 256, 0, stream>>>(sdw, sdw_bf, C_DIM * HS_DIM / 4);
  cvt_bf16_kernel<<<4096, 256, 0, stream>>>(upw, upw_bf, E_NUM * 2 * H_DIM * C_DIM / 4);
  cvt_bf16_kernel<<<4096, 256, 0, stream>>>(dww, dww_bf, E_NUM * C_DIM * H_DIM / 4);

  gate_topk_kernel<<<N_TOK, 256, 0, stream>>>(x, gw, gb, tok_e, tok_w, counts);
  scan_route_kernel<<<1, 64, 0, stream>>>(counts, off_pad, tile_e, tile_s0, ntiles, totrows);
  build_slots_kernel<<<32, 256, 0, stream>>>(tok_e, off_pad, cursor, slot_tok, slot_of);

  // shared up: gu = x @ sgw^T   [8192 x 5632]; 32 mt x 22 nt = 704 blocks
  gemm256<false, false, false><<<32 * 22, 512, 0, stream>>>(
      x_bf, sgw_bf, gu, 2 * HS_DIM, C_DIM, 22,
      nullptr, nullptr, nullptr, nullptr, 0);
  // shared swiglu: y first, g second -> sil_off=HS, mul_off=0
  swiglu_kernel<<<dim3(2, N_TOK), 256, 0, stream>>>(gu, h_sh, HS_DIM, HS_DIM, 0, nullptr);

  // routed up: gu = gather(x) @ upw[e]^T; 72 mt x 11 nt = 792 blocks
  gemm256<true, true, false><<<MAXT256 * 11, 512, 0, stream>>>(
      x_bf, upw_bf, gu, 2 * H_DIM, C_DIM, 11,
      tile_e, tile_s0, ntiles, slot_tok, (long)(2 * H_DIM) * C_DIM);
  // routed swiglu: g first, u second -> sil_off=0, mul_off=H
  swiglu_kernel<<<dim3(1, NRPAD), 256, 0, stream>>>(gu, h_rt, H_DIM, 0, H_DIM, totrows);

  // shared down: out = h_sh @ sdw^T (f32 store); 32 mt x 8 nt = 256 blocks
  gemm256<false, false, true><<<32 * 8, 512, 0, stream>>>(
      h_sh, sdw_bf, out, C_DIM, HS_DIM, 8,
      nullptr, nullptr, nullptr, nullptr, 0);
  // routed down: p_rt[slot] = h_rt[slot] @ dww[e]^T (bf16); 72 mt x 8 nt
  gemm256<false, true, false><<<MAXT256 * 8, 512, 0, stream>>>(
      h_rt, dww_bf, p_rt, C_DIM, H_DIM, 8,
      tile_e, tile_s0, ntiles, nullptr, (long)C_DIM * H_DIM);

  // combine: out[tok] += w0*p_rt[slot0] + w1*p_rt[slot1]
  combine_kernel<<<N_TOK, 256, 0, stream>>>(out, p_rt, slot_of, tok_w);
}

// Round 6
// 1074.249 us; speedup vs baseline: 3.9853x; 1.0331x over previous
//
#include <hip/hip_runtime.h>
#include <hip/hip_bf16.h>
#include <stdint.h>

// Problem constants (from setup_inputs)
#define N_TOK 8192
#define C_DIM 2048
#define E_NUM 8
#define H_DIM 1408
#define HS_DIM 2816
#define NRPAD 18432      // 16384 routed slots + per-expert padding to 256
#define MAXT256 72       // 64 full tiles + 8 partial

typedef unsigned short u16;
typedef float f32x4_t __attribute__((ext_vector_type(4)));
typedef short bf16x8_t __attribute__((ext_vector_type(8)));

__device__ __forceinline__ u16 f2bf(float f) {
  union { float f; uint32_t u; } c; c.f = f;
  uint32_t u = c.u;
  return (u16)((u + 0x7fffu + ((u >> 16) & 1u)) >> 16);
}
__device__ __forceinline__ float bf2f(u16 b) {
  union { uint32_t u; float f; } c; c.u = ((uint32_t)b) << 16;
  return c.f;
}

__device__ __forceinline__ void async_copy16(const u16* gsrc, u16* ldst) {
  __builtin_amdgcn_global_load_lds(
      (const __attribute__((address_space(1))) void*)gsrc,
      (__attribute__((address_space(3))) void*)ldst, 16, 0, 0);
}

#define BARRIER() asm volatile("s_barrier" ::: "memory")
#define WAITV4()  asm volatile("s_waitcnt vmcnt(4)" ::: "memory")
#define WAITV0()  asm volatile("s_waitcnt vmcnt(0)" ::: "memory")

// ---------------- fp32 -> bf16 conversion ----------------
__global__ __launch_bounds__(256) void cvt_bf16_kernel(
    const float* __restrict__ in, u16* __restrict__ out, int n4) {
  int i = blockIdx.x * blockDim.x + threadIdx.x;
  int stride = gridDim.x * blockDim.x;
  for (; i < n4; i += stride) {
    float4 v = ((const float4*)in)[i];
    ushort4 u;
    u.x = f2bf(v.x); u.y = f2bf(v.y); u.z = f2bf(v.z); u.w = f2bf(v.w);
    ((ushort4*)out)[i] = u;
  }
}

// ---------------- gate: fp32 scores, top-2, renorm weights ----------------
__global__ __launch_bounds__(256) void gate_topk_kernel(
    const float* __restrict__ x, const float* __restrict__ gw,
    const float* __restrict__ gbias,
    int* __restrict__ tok_e, float* __restrict__ tok_w, int* __restrict__ counts) {
  int n = blockIdx.x;
  const float* xr = x + (size_t)n * C_DIM;
  int t = threadIdx.x;
  float acc[E_NUM];
#pragma unroll
  for (int e = 0; e < E_NUM; ++e) acc[e] = 0.f;
  for (int k0 = t * 4; k0 < C_DIM; k0 += 1024) {
    float4 xv = *(const float4*)(xr + k0);
#pragma unroll
    for (int e = 0; e < E_NUM; ++e) {
      float4 gv = *(const float4*)(gw + e * C_DIM + k0);
      acc[e] += xv.x * gv.x + xv.y * gv.y + xv.z * gv.z + xv.w * gv.w;
    }
  }
#pragma unroll
  for (int e = 0; e < E_NUM; ++e)
    for (int off = 32; off > 0; off >>= 1) acc[e] += __shfl_xor(acc[e], off, 64);
  __shared__ float sred[4][E_NUM];
  int wid = t >> 6, lane = t & 63;
  if (lane == 0) {
#pragma unroll
    for (int e = 0; e < E_NUM; ++e) sred[wid][e] = acc[e];
  }
  __syncthreads();
  if (t == 0) {
    float sc[E_NUM];
#pragma unroll
    for (int e = 0; e < E_NUM; ++e) {
      float s = sred[0][e] + sred[1][e] + sred[2][e] + sred[3][e];
      sc[e] = 1.f / (1.f + expf(-s));
    }
    int e0 = 0; float k0v = sc[0] + gbias[0];
    for (int e = 1; e < E_NUM; ++e) {
      float ke = sc[e] + gbias[e];
      if (ke > k0v) { k0v = ke; e0 = e; }
    }
    int e1 = -1; float k1v = -1e30f;
    for (int e = 0; e < E_NUM; ++e) {
      if (e == e0) continue;
      float ke = sc[e] + gbias[e];
      if (ke > k1v) { k1v = ke; e1 = e; }
    }
    float w0 = sc[e0], w1 = sc[e1];
    float s = w0 + w1;
    w0 /= s; w1 /= s;
    tok_e[2 * n] = e0; tok_e[2 * n + 1] = e1;
    tok_w[2 * n] = w0; tok_w[2 * n + 1] = w1;
    atomicAdd(&counts[e0], 1);
    atomicAdd(&counts[e1], 1);
  }
}

// ---------------- routing scan: 256-padded offsets + tile table ----------------
__global__ void scan_route_kernel(const int* __restrict__ counts,
                                  int* __restrict__ off_pad,
                                  int* __restrict__ tile_e, int* __restrict__ tile_s0,
                                  int* __restrict__ ntiles, int* __restrict__ totrows) {
  if (threadIdx.x == 0 && blockIdx.x == 0) {
    int off = 0, t = 0;
    for (int e = 0; e < E_NUM; ++e) {
      off_pad[e] = off;
      int tiles = (counts[e] + 255) >> 8;
      for (int i = 0; i < tiles; ++i) { tile_e[t] = e; tile_s0[t] = off + i * 256; ++t; }
      off += tiles * 256;
    }
    *ntiles = t;
    *totrows = off;
  }
}

__global__ __launch_bounds__(256) void build_slots_kernel(
    const int* __restrict__ tok_e, const int* __restrict__ off_pad,
    int* __restrict__ cursor, int* __restrict__ slot_tok, int* __restrict__ slot_of) {
  int n = blockIdx.x * blockDim.x + threadIdx.x;
  if (n >= N_TOK) return;
#pragma unroll
  for (int j = 0; j < 2; ++j) {
    int e = tok_e[2 * n + j];
    int pos = atomicAdd(&cursor[e], 1);
    int s = off_pad[e] + pos;
    slot_tok[s] = n;
    slot_of[2 * n + j] = s;
  }
}

// ---------------- 256x256x64 8-phase bf16 GEMM (T2+T3+T4+T5) ----------------
// 512 threads = 8 waves (2 wm x 4 wn); per-wave output 128x64 (8x4 frags).
// LDS per buffer: A,B each [2 ks][256 r][32 k] bf16 (k-major halves so each
// half-tile is contiguous for global_load_lds). Double-buffered = 128 KiB.
// T2 swizzle: LDS col-group ^= (row>>1)&3 (16B groups), via pre-swizzled
// global source (linear LDS dest) + same XOR on ds_read. Bank-quad per lane
// = (fr&1)*4 + (kq^((fr>>1)&3)): each 8-lane group covers all 8 quads.
// Schedule per K-tile: 4 phases {(qm0,ks0)(qm1,ks0)(qm0,ks1)(qm1,ks1)}, each
// stages one half-tile of the NEXT K-tile (2 loads); counted vmcnt(4) only at
// phases 2 and 4 (2 HTs in flight), never 0 in the main loop.
template <bool GATHER, bool ROUTE, bool F32OUT>
__global__ __launch_bounds__(512, 2) void gemm256(
    const u16* __restrict__ A, const u16* __restrict__ B,
    void* __restrict__ Out, int ldo, int K, int nbn,
    const int* __restrict__ tile_e, const int* __restrict__ tile_s0,
    const int* __restrict__ ntiles, const int* __restrict__ slot_tok,
    long estride) {
  // XCD-contiguous chunks; within a chunk, 4-mt bands swept across nt.
  const int chunk = gridDim.x >> 3;
  const int orig = blockIdx.x;
  const int l = (orig & 7) * chunk + (orig >> 3);
  const int bandsz = nbn << 2;
  const int band = l / bandsz;
  const int rem = l - band * bandsz;
  const int nt = rem >> 2;
  const int mt = (band << 2) + (rem & 3);
  if (ROUTE) { if (mt >= *ntiles) return; }
  const int m0 = ROUTE ? tile_s0[mt] : (mt << 8);
  const u16* Bb = B + (ROUTE ? (size_t)tile_e[mt] * (size_t)estride : 0);
  const int n0 = nt << 8;

  __shared__ u16 lds[65536];   // [buf(2)][mat(2)][ks(2)][256][32]

  const int t = threadIdx.x;
  const int w = t >> 6, lane = t & 63;
  const int wst = w << 9;                  // wave LDS slice within an issue
  // staging source pointers (pre-swizzled global col-group)
  const int rt2 = t >> 2;                  // staged row 0..127
  const int coff = (((t & 3) ^ ((rt2 >> 1) & 3)) << 3);
  const u16* aS[2]; const u16* bS[2];
#pragma unroll
  for (int j = 0; j < 2; ++j) {
    int r = (j << 7) + rt2;
    int arow = GATHER ? slot_tok[m0 + r] : (m0 + r);
    aS[j] = A + (size_t)arow * K + coff;
    bS[j] = Bb + (size_t)(n0 + r) * K + coff;
  }

  const int wm = w >> 2, wn = w & 3;
  const int fr = lane & 15, kq = lane >> 4;
  const int swz = ((kq ^ ((fr >> 1) & 3)) << 3);   // u16 col offset in 32-u16 row

  f32x4_t acc[8][4];
  f32x4_t zero4 = {0.f, 0.f, 0.f, 0.f};
#pragma unroll
  for (int m = 0; m < 8; ++m)
#pragma unroll
    for (int n = 0; n < 4; ++n) acc[m][n] = zero4;

#define STG_A(KS) \
  async_copy16(aS[0] + kst + (KS)*32, &lds[nxtb + (KS)*8192 + wst]); \
  async_copy16(aS[1] + kst + (KS)*32, &lds[nxtb + (KS)*8192 + 4096 + wst]);
#define STG_B(KS) \
  async_copy16(bS[0] + kst + (KS)*32, &lds[nxtb + 16384 + (KS)*8192 + wst]); \
  async_copy16(bS[1] + kst + (KS)*32, &lds[nxtb + 16384 + (KS)*8192 + 4096 + wst]);
#define LDA(QM, KS) \
  _Pragma("unroll") \
  for (int m = 0; m < 4; ++m) { \
    int row = (wm << 7) + (QM)*64 + (m << 4) + fr; \
    afr[m] = *(const bf16x8_t*)&lds[cur + (KS)*8192 + (row << 5) + swz]; \
  }
#define LDB(KS) \
  _Pragma("unroll") \
  for (int n = 0; n < 4; ++n) { \
    int row = (wn << 6) + (n << 4) + fr; \
    bfr[n] = *(const bf16x8_t*)&lds[cur + 16384 + (KS)*8192 + (row << 5) + swz]; \
  }
#define MFMA16(QM) \
  __builtin_amdgcn_s_setprio(1); \
  _Pragma("unroll") \
  for (int m = 0; m < 4; ++m) \
    _Pragma("unroll") \
    for (int n = 0; n < 4; ++n) \
      acc[(QM)*4 + m][n] = __builtin_amdgcn_mfma_f32_16x16x32_bf16( \
          afr[m], bfr[n], acc[(QM)*4 + m][n], 0, 0, 0); \
  __builtin_amdgcn_s_setprio(0);

  const int KT = K >> 6;
  // prologue: stage K-tile 0 into buf0 (order A0,B0,A1,B1), wait first 2 HTs
  {
    const int nxtb = 0, kst = 0;
    STG_A(0); STG_B(0); STG_A(1); STG_B(1);
  }
  WAITV4();
  BARRIER();

  for (int kt = 0; kt < KT; ++kt) {
    const int cur = (kt & 1) << 15;
    const int nxtb = ((kt + 1) & 1) << 15;
    const int kst = (kt + 1 < KT ? kt + 1 : kt) << 6;   // last tile: junk re-stage
    bf16x8_t afr[4], bfr[4];

    // phase 1: (qm0, ks0); stage A-ks0 of next
    LDB(0); LDA(0, 0); STG_A(0);
    BARRIER();
    MFMA16(0);
    BARRIER();
    // phase 2: (qm1, ks0); stage B-ks0
    LDA(1, 0); STG_B(0);
    BARRIER();
    MFMA16(1);
    WAITV4();        // A1(kt),B1(kt) landed; A0/B0(kt+1) may fly
    BARRIER();
    // phase 3: (qm0, ks1); stage A-ks1
    LDB(1); LDA(0, 1); STG_A(1);
    BARRIER();
    MFMA16(0);
    BARRIER();
    // phase 4: (qm1, ks1); stage B-ks1
    LDA(1, 1); STG_B(1);
    BARRIER();
    MFMA16(1);
    WAITV4();        // A0(kt+1),B0(kt+1) landed; A1/B1(kt+1) may fly
    BARRIER();
  }
  WAITV0();          // drain junk stages before LDS dealloc

  // epilogue
#pragma unroll
  for (int mf = 0; mf < 8; ++mf) {
    const int rb = (wm << 7) + (mf << 4) + (kq << 2);
#pragma unroll
    for (int rr = 0; rr < 4; ++rr) {
      const int row = m0 + rb + rr;
      if (F32OUT) {
        float* orow = (float*)Out + (size_t)row * ldo;
#pragma unroll
        for (int n = 0; n < 4; ++n)
          orow[n0 + (wn << 6) + (n << 4) + fr] = acc[mf][n][rr];
      } else {
        u16* orow = (u16*)Out + (size_t)row * ldo;
#pragma unroll
        for (int n = 0; n < 4; ++n)
          orow[n0 + (wn << 6) + (n << 4) + fr] = f2bf(acc[mf][n][rr]);
      }
    }
  }
#undef STG_A
#undef STG_B
#undef LDA
#undef LDB
#undef MFMA16
}

// ---------------- SwiGLU elementwise ----------------
__global__ __launch_bounds__(256) void swiglu_kernel(
    const u16* __restrict__ gu, u16* __restrict__ h,
    int width, int sil_off, int mul_off, const int* __restrict__ rowbound) {
  int row = blockIdx.y;
  if (rowbound && row >= *rowbound) return;
  int j8 = blockIdx.x * blockDim.x + threadIdx.x;
  if (j8 * 8 >= width) return;
  const u16* base = gu + (size_t)row * 2 * width;
  union { uint4 v; u16 s[8]; } G, U, R;
  G.v = *(const uint4*)(base + sil_off + j8 * 8);
  U.v = *(const uint4*)(base + mul_off + j8 * 8);
#pragma unroll
  for (int e = 0; e < 8; ++e) {
    float g = bf2f(G.s[e]);
    float u = bf2f(U.s[e]);
    float hv = (g / (1.f + __expf(-g))) * u;
    R.s[e] = f2bf(hv);
  }
  *(uint4*)(h + (size_t)row * width + j8 * 8) = R.v;
}

// ---------------- combine: out[tok] += w0*p[slot0] + w1*p[slot1] ----------------
__global__ __launch_bounds__(256) void combine_kernel(
    float* __restrict__ out, const u16* __restrict__ p_rt,
    const int* __restrict__ slot_of, const float* __restrict__ tok_w) {
  int tok = blockIdx.x;
  int j = threadIdx.x;               // 256 threads x 8 cols = 2048
  int s0 = slot_of[2 * tok], s1 = slot_of[2 * tok + 1];
  float w0 = tok_w[2 * tok], w1 = tok_w[2 * tok + 1];
  const u16* r0 = p_rt + (size_t)s0 * C_DIM + j * 8;
  const u16* r1 = p_rt + (size_t)s1 * C_DIM + j * 8;
  float* o = out + (size_t)tok * C_DIM + j * 8;
  union { uint4 v; u16 s[8]; } P0, P1;
  P0.v = *(const uint4*)r0;
  P1.v = *(const uint4*)r1;
  float4 o0 = *(const float4*)o;
  float4 o1 = *(const float4*)(o + 4);
  float r[8];
#pragma unroll
  for (int e = 0; e < 8; ++e) r[e] = w0 * bf2f(P0.s[e]) + w1 * bf2f(P1.s[e]);
  o0.x += r[0]; o0.y += r[1]; o0.z += r[2]; o0.w += r[3];
  o1.x += r[4]; o1.y += r[5]; o1.z += r[6]; o1.w += r[7];
  *(float4*)o = o0;
  *(float4*)(o + 4) = o1;
}

// ---------------- host launch ----------------
extern "C" void kernel_launch(void* const* d_in, const int* in_sizes, int n_in,
                              void* d_out, int out_size, void* d_ws, size_t ws_size,
                              hipStream_t stream) {
  const float* x   = (const float*)d_in[0];
  const float* gw  = (const float*)d_in[1];
  const float* gb  = (const float*)d_in[2];
  const float* sgw = (const float*)d_in[3];
  const float* sdw = (const float*)d_in[4];
  const float* upw = (const float*)d_in[5];
  const float* dww = (const float*)d_in[6];
  float* out = (float*)d_out;

  char* ws = (char*)d_ws;
  size_t off = 0;
  auto take = [&](size_t bytes) -> void* {
    size_t o = (off + 255) & ~(size_t)255;
    off = o + bytes;
    return (void*)(ws + o);
  };

  u16* x_bf   = (u16*)take((size_t)N_TOK * C_DIM * 2);
  u16* sgw_bf = (u16*)take((size_t)(2 * HS_DIM) * C_DIM * 2);
  u16* sdw_bf = (u16*)take((size_t)C_DIM * HS_DIM * 2);
  u16* upw_bf = (u16*)take((size_t)E_NUM * (2 * H_DIM) * C_DIM * 2);
  u16* dww_bf = (u16*)take((size_t)E_NUM * C_DIM * H_DIM * 2);
  u16* gu     = (u16*)take((size_t)NRPAD * (2 * H_DIM) * 2);   // covers 8192x5632 too
  u16* h_sh   = (u16*)take((size_t)N_TOK * HS_DIM * 2);
  u16* h_rt   = upw_bf;  // alias: upw_bf dead after routed-up GEMM (52MB <= 92MB)
  u16* p_rt   = gu;      // alias: gu dead after routed swiglu (76MB <= 104MB)

  int*   tok_e    = (int*)take((size_t)N_TOK * 2 * 4);
  float* tok_w    = (float*)take((size_t)N_TOK * 2 * 4);
  int*   slot_of  = (int*)take((size_t)N_TOK * 2 * 4);
  int*   slot_tok = (int*)take((size_t)NRPAD * 4);      // zeroed span start
  int*   counts   = (int*)take(E_NUM * 4);
  int*   cursor   = (int*)take(E_NUM * 4);
  int*   off_pad  = (int*)take(E_NUM * 4);
  int*   ntiles   = (int*)take(4);
  int*   totrows  = (int*)take(4);
  int*   tile_e   = (int*)take(MAXT256 * 4);
  int*   tile_s0  = (int*)take(MAXT256 * 4);
  (void)ws_size; (void)in_sizes; (void)n_in; (void)out_size;

  // zero slot_tok + counts + cursor (contiguous span)
  size_t z0 = (size_t)((char*)slot_tok - ws);
  size_t z1 = (size_t)((char*)cursor - ws) + E_NUM * 4;
  hipMemsetAsync(ws + z0, 0, z1 - z0, stream);

  // weight/activation bf16 conversion
  cvt_bf16_kernel<<<2048, 256, 0, stream>>>(x, x_bf, N_TOK * C_DIM / 4);
  cvt_bf16_kernel<<<2048, 256, 0, stream>>>(sgw, sgw_bf, 2 * HS_DIM * C_DIM / 4);
  cvt_bf16_kernel<<<2048, 256, 0, stream>>>(sdw, sdw_bf, C_DIM * HS_DIM / 4);
  cvt_bf16_kernel<<<4096, 256, 0, stream>>>(upw, upw_bf, E_NUM * 2 * H_DIM * C_DIM / 4);
  cvt_bf16_kernel<<<4096, 256, 0, stream>>>(dww, dww_bf, E_NUM * C_DIM * H_DIM / 4);

  gate_topk_kernel<<<N_TOK, 256, 0, stream>>>(x, gw, gb, tok_e, tok_w, counts);
  scan_route_kernel<<<1, 64, 0, stream>>>(counts, off_pad, tile_e, tile_s0, ntiles, totrows);
  build_slots_kernel<<<32, 256, 0, stream>>>(tok_e, off_pad, cursor, slot_tok, slot_of);

  // shared up: gu = x @ sgw^T   [8192 x 5632]; 32 mt x 22 nt = 704 blocks
  gemm256<false, false, false><<<32 * 22, 512, 0, stream>>>(
      x_bf, sgw_bf, gu, 2 * HS_DIM, C_DIM, 22,
      nullptr, nullptr, nullptr, nullptr, 0);
  // shared swiglu: y first, g second -> sil_off=HS, mul_off=0
  swiglu_kernel<<<dim3(2, N_TOK), 256, 0, stream>>>(gu, h_sh, HS_DIM, HS_DIM, 0, nullptr);

  // routed up: gu = gather(x) @ upw[e]^T; 72 mt x 11 nt = 792 blocks
  gemm256<true, true, false><<<MAXT256 * 11, 512, 0, stream>>>(
      x_bf, upw_bf, gu, 2 * H_DIM, C_DIM, 11,
      tile_e, tile_s0, ntiles, slot_tok, (long)(2 * H_DIM) * C_DIM);
  // routed swiglu: g first, u second -> sil_off=0, mul_off=H
  swiglu_kernel<<<dim3(1, NRPAD), 256, 0, stream>>>(gu, h_rt, H_DIM, 0, H_DIM, totrows);

  // shared down: out = h_sh @ sdw^T (f32 store); 32 mt x 8 nt = 256 blocks
  gemm256<false, false, true><<<32 * 8, 512, 0, stream>>>(
      h_sh, sdw_bf, out, C_DIM, HS_DIM, 8,
      nullptr, nullptr, nullptr, nullptr, 0);
  // routed down: p_rt[slot] = h_rt[slot] @ dww[e]^T (bf16); 72 mt x 8 nt
  gemm256<false, true, false><<<MAXT256 * 8, 512, 0, stream>>>(
      h_rt, dww_bf, p_rt, C_DIM, H_DIM, 8,
      tile_e, tile_s0, ntiles, nullptr, (long)C_DIM * H_DIM);

  // combine: out[tok] += w0*p_rt[slot0] + w1*p_rt[slot1]
  combine_kernel<<<N_TOK, 256, 0, stream>>>(out, p_rt, slot_of, tok_w);
}

// Round 8
// 1025.644 us; speedup vs baseline: 4.1742x; 1.0474x over previous
//
#include <hip/hip_runtime.h>
#include <hip/hip_bf16.h>
#include <stdint.h>

// Problem constants (from setup_inputs)
#define N_TOK 8192
#define C_DIM 2048
#define E_NUM 8
#define H_DIM 1408
#define HS_DIM 2816
#define NRPAD 18432      // 16384 routed slots + per-expert padding to 256
#define MAXT256 72       // 64 full tiles + 8 partial

typedef unsigned short u16;
typedef float f32x4_t __attribute__((ext_vector_type(4)));
typedef short bf16x8_t __attribute__((ext_vector_type(8)));

__device__ __forceinline__ u16 f2bf(float f) {
  union { float f; uint32_t u; } c; c.f = f;
  uint32_t u = c.u;
  return (u16)((u + 0x7fffu + ((u >> 16) & 1u)) >> 16);
}
__device__ __forceinline__ float bf2f(u16 b) {
  union { uint32_t u; float f; } c; c.u = ((uint32_t)b) << 16;
  return c.f;
}

__device__ __forceinline__ void async_copy16(const u16* gsrc, u16* ldst) {
  __builtin_amdgcn_global_load_lds(
      (const __attribute__((address_space(1))) void*)gsrc,
      (__attribute__((address_space(3))) void*)ldst, 16, 0, 0);
}

#define BARRIER() asm volatile("s_barrier" ::: "memory")
#define WAITV4()  asm volatile("s_waitcnt vmcnt(4)" ::: "memory")
#define WAITV0()  asm volatile("s_waitcnt vmcnt(0)" ::: "memory")

// ---------------- fp32 -> bf16 conversion ----------------
__global__ __launch_bounds__(256) void cvt_bf16_kernel(
    const float* __restrict__ in, u16* __restrict__ out, int n4) {
  int i = blockIdx.x * blockDim.x + threadIdx.x;
  int stride = gridDim.x * blockDim.x;
  for (; i < n4; i += stride) {
    float4 v = ((const float4*)in)[i];
    ushort4 u;
    u.x = f2bf(v.x); u.y = f2bf(v.y); u.z = f2bf(v.z); u.w = f2bf(v.w);
    ((ushort4*)out)[i] = u;
  }
}

// ---------------- gate: fp32 scores, top-2, renorm weights ----------------
__global__ __launch_bounds__(256) void gate_topk_kernel(
    const float* __restrict__ x, const float* __restrict__ gw,
    const float* __restrict__ gbias,
    int* __restrict__ tok_e, float* __restrict__ tok_w, int* __restrict__ counts) {
  int n = blockIdx.x;
  const float* xr = x + (size_t)n * C_DIM;
  int t = threadIdx.x;
  float acc[E_NUM];
#pragma unroll
  for (int e = 0; e < E_NUM; ++e) acc[e] = 0.f;
  for (int k0 = t * 4; k0 < C_DIM; k0 += 1024) {
    float4 xv = *(const float4*)(xr + k0);
#pragma unroll
    for (int e = 0; e < E_NUM; ++e) {
      float4 gv = *(const float4*)(gw + e * C_DIM + k0);
      acc[e] += xv.x * gv.x + xv.y * gv.y + xv.z * gv.z + xv.w * gv.w;
    }
  }
#pragma unroll
  for (int e = 0; e < E_NUM; ++e)
    for (int off = 32; off > 0; off >>= 1) acc[e] += __shfl_xor(acc[e], off, 64);
  __shared__ float sred[4][E_NUM];
  int wid = t >> 6, lane = t & 63;
  if (lane == 0) {
#pragma unroll
    for (int e = 0; e < E_NUM; ++e) sred[wid][e] = acc[e];
  }
  __syncthreads();
  if (t == 0) {
    float sc[E_NUM];
#pragma unroll
    for (int e = 0; e < E_NUM; ++e) {
      float s = sred[0][e] + sred[1][e] + sred[2][e] + sred[3][e];
      sc[e] = 1.f / (1.f + expf(-s));
    }
    int e0 = 0; float k0v = sc[0] + gbias[0];
    for (int e = 1; e < E_NUM; ++e) {
      float ke = sc[e] + gbias[e];
      if (ke > k0v) { k0v = ke; e0 = e; }
    }
    int e1 = -1; float k1v = -1e30f;
    for (int e = 0; e < E_NUM; ++e) {
      if (e == e0) continue;
      float ke = sc[e] + gbias[e];
      if (ke > k1v) { k1v = ke; e1 = e; }
    }
    float w0 = sc[e0], w1 = sc[e1];
    float s = w0 + w1;
    w0 /= s; w1 /= s;
    tok_e[2 * n] = e0; tok_e[2 * n + 1] = e1;
    tok_w[2 * n] = w0; tok_w[2 * n + 1] = w1;
    atomicAdd(&counts[e0], 1);
    atomicAdd(&counts[e1], 1);
  }
}

// ---------------- routing scan: 256-padded offsets + tile table ----------------
__global__ void scan_route_kernel(const int* __restrict__ counts,
                                  int* __restrict__ off_pad,
                                  int* __restrict__ tile_e, int* __restrict__ tile_s0,
                                  int* __restrict__ ntiles) {
  if (threadIdx.x == 0 && blockIdx.x == 0) {
    int off = 0, t = 0;
    for (int e = 0; e < E_NUM; ++e) {
      off_pad[e] = off;
      int tiles = (counts[e] + 255) >> 8;
      for (int i = 0; i < tiles; ++i) { tile_e[t] = e; tile_s0[t] = off + i * 256; ++t; }
      off += tiles * 256;
    }
    *ntiles = t;
  }
}

__global__ __launch_bounds__(256) void build_slots_kernel(
    const int* __restrict__ tok_e, const int* __restrict__ off_pad,
    int* __restrict__ cursor, int* __restrict__ slot_tok, int* __restrict__ slot_of) {
  int n = blockIdx.x * blockDim.x + threadIdx.x;
  if (n >= N_TOK) return;
#pragma unroll
  for (int j = 0; j < 2; ++j) {
    int e = tok_e[2 * n + j];
    int pos = atomicAdd(&cursor[e], 1);
    int s = off_pad[e] + pos;
    slot_tok[s] = n;
    slot_of[2 * n + j] = s;
  }
}

// ---------------- 256x256x64 8-phase bf16 GEMM (T2+T3+T4+T5) ----------------
// Round-6 proven schedule (8 barriers/K-tile, vmcnt(4) at P2/P4, never 0).
// FUSE: up-proj + SwiGLU fusion. B tile rows interleave 16-row blocks from the
// sil-half and mul-half of the weight (r>>4 even -> sil, odd -> mul), so
// acc[m][2j] (g) and acc[m][2j+1] (u) for the SAME h column sit in the same
// lane; epilogue writes h = silu(g)*u directly (128 h cols per block).
template <bool GATHER, bool ROUTE, bool F32OUT, bool FUSE>
__global__ __launch_bounds__(512, 2) void gemm256(
    const u16* __restrict__ A, const u16* __restrict__ B,
    void* __restrict__ Out, int ldo, int K, int nbn,
    const int* __restrict__ tile_e, const int* __restrict__ tile_s0,
    const int* __restrict__ ntiles, const int* __restrict__ slot_tok,
    long estride, int silbase, int mulbase) {
  // XCD-contiguous chunks; within a chunk, 4-mt bands swept across nt.
  const int chunk = gridDim.x >> 3;
  const int orig = blockIdx.x;
  const int l = (orig & 7) * chunk + (orig >> 3);
  const int bandsz = nbn << 2;
  const int band = l / bandsz;
  const int rem = l - band * bandsz;
  const int nt = rem >> 2;
  const int mt = (band << 2) + (rem & 3);
  if (ROUTE) { if (mt >= *ntiles) return; }
  const int m0 = ROUTE ? tile_s0[mt] : (mt << 8);
  const u16* Bb = B + (ROUTE ? (size_t)tile_e[mt] * (size_t)estride : 0);
  const int n0 = nt << 8;   // acc-col base (unfused)
  const int h0 = nt << 7;   // fused h-col base

  __shared__ u16 lds[65536];   // [buf(2)][mat(2)][ks(2)][256][32]

  const int t = threadIdx.x;
  const int w = t >> 6, lane = t & 63;
  const int wst = w << 9;                  // wave LDS slice within an issue
  // staging source pointers (pre-swizzled global col-group)
  const int rt2 = t >> 2;                  // staged row 0..127
  const int coff = (((t & 3) ^ ((rt2 >> 1) & 3)) << 3);
  const u16* aS[2]; const u16* bS[2];
#pragma unroll
  for (int j = 0; j < 2; ++j) {
    int r = (j << 7) + rt2;
    int arow = GATHER ? slot_tok[m0 + r] : (m0 + r);
    aS[j] = A + (size_t)arow * K + coff;
    int grow;
    if (FUSE) {
      // tile B-row r -> weight row: blk=r>>4 (even: sil, odd: mul)
      grow = (((r >> 4) & 1) ? mulbase : silbase) + h0 + ((r >> 5) << 4) + (r & 15);
    } else {
      grow = n0 + r;
    }
    bS[j] = Bb + (size_t)grow * K + coff;
  }

  const int wm = w >> 2, wn = w & 3;
  const int fr = lane & 15, kq = lane >> 4;
  const int swz = ((kq ^ ((fr >> 1) & 3)) << 3);   // u16 col offset in 32-u16 row

  f32x4_t acc[8][4];
  f32x4_t zero4 = {0.f, 0.f, 0.f, 0.f};
#pragma unroll
  for (int m = 0; m < 8; ++m)
#pragma unroll
    for (int n = 0; n < 4; ++n) acc[m][n] = zero4;

#define STG_A(KS) \
  async_copy16(aS[0] + kst + (KS)*32, &lds[nxtb + (KS)*8192 + wst]); \
  async_copy16(aS[1] + kst + (KS)*32, &lds[nxtb + (KS)*8192 + 4096 + wst]);
#define STG_B(KS) \
  async_copy16(bS[0] + kst + (KS)*32, &lds[nxtb + 16384 + (KS)*8192 + wst]); \
  async_copy16(bS[1] + kst + (KS)*32, &lds[nxtb + 16384 + (KS)*8192 + 4096 + wst]);
#define LDA(QM, KS) \
  _Pragma("unroll") \
  for (int m = 0; m < 4; ++m) { \
    int row = (wm << 7) + (QM)*64 + (m << 4) + fr; \
    afr[m] = *(const bf16x8_t*)&lds[cur + (KS)*8192 + (row << 5) + swz]; \
  }
#define LDB(KS) \
  _Pragma("unroll") \
  for (int n = 0; n < 4; ++n) { \
    int row = (wn << 6) + (n << 4) + fr; \
    bfr[n] = *(const bf16x8_t*)&lds[cur + 16384 + (KS)*8192 + (row << 5) + swz]; \
  }
#define MFMA16(QM) \
  __builtin_amdgcn_s_setprio(1); \
  _Pragma("unroll") \
  for (int m = 0; m < 4; ++m) \
    _Pragma("unroll") \
    for (int n = 0; n < 4; ++n) \
      acc[(QM)*4 + m][n] = __builtin_amdgcn_mfma_f32_16x16x32_bf16( \
          afr[m], bfr[n], acc[(QM)*4 + m][n], 0, 0, 0); \
  __builtin_amdgcn_s_setprio(0);

  const int KT = K >> 6;
  // prologue: stage K-tile 0 into buf0 (order A0,B0,A1,B1), wait first 2 HTs
  {
    const int nxtb = 0, kst = 0;
    STG_A(0); STG_B(0); STG_A(1); STG_B(1);
  }
  WAITV4();
  BARRIER();

  for (int kt = 0; kt < KT; ++kt) {
    const int cur = (kt & 1) << 15;
    const int nxtb = ((kt + 1) & 1) << 15;
    const int kst = (kt + 1 < KT ? kt + 1 : kt) << 6;   // last tile: junk re-stage
    bf16x8_t afr[4], bfr[4];

    // phase 1: (qm0, ks0); stage A-ks0 of next
    LDB(0); LDA(0, 0); STG_A(0);
    BARRIER();
    MFMA16(0);
    BARRIER();
    // phase 2: (qm1, ks0); stage B-ks0
    LDA(1, 0); STG_B(0);
    BARRIER();
    MFMA16(1);
    WAITV4();        // A1(kt),B1(kt) landed; A0/B0(kt+1) may fly
    BARRIER();
    // phase 3: (qm0, ks1); stage A-ks1
    LDB(1); LDA(0, 1); STG_A(1);
    BARRIER();
    MFMA16(0);
    BARRIER();
    // phase 4: (qm1, ks1); stage B-ks1
    LDA(1, 1); STG_B(1);
    BARRIER();
    MFMA16(1);
    WAITV4();        // A0(kt+1),B0(kt+1) landed; A1/B1(kt+1) may fly
    BARRIER();
  }
  WAITV0();          // drain junk stages before LDS dealloc

  // epilogue
#pragma unroll
  for (int mf = 0; mf < 8; ++mf) {
    const int rb = (wm << 7) + (mf << 4) + (kq << 2);
#pragma unroll
    for (int rr = 0; rr < 4; ++rr) {
      const int row = m0 + rb + rr;
      if (FUSE) {
        u16* orow = (u16*)Out + (size_t)row * ldo;
#pragma unroll
        for (int jj = 0; jj < 2; ++jj) {
          float g = acc[mf][2 * jj][rr];
          float uu = acc[mf][2 * jj + 1][rr];
          float hv = (g / (1.f + __expf(-g))) * uu;
          orow[h0 + (wn << 5) + (jj << 4) + fr] = f2bf(hv);
        }
      } else if (F32OUT) {
        float* orow = (float*)Out + (size_t)row * ldo;
#pragma unroll
        for (int n = 0; n < 4; ++n)
          orow[n0 + (wn << 6) + (n << 4) + fr] = acc[mf][n][rr];
      } else {
        u16* orow = (u16*)Out + (size_t)row * ldo;
#pragma unroll
        for (int n = 0; n < 4; ++n)
          orow[n0 + (wn << 6) + (n << 4) + fr] = f2bf(acc[mf][n][rr]);
      }
    }
  }
#undef STG_A
#undef STG_B
#undef LDA
#undef LDB
#undef MFMA16
}

// ---------------- combine: out[tok] += w0*p[slot0] + w1*p[slot1] ----------------
__global__ __launch_bounds__(256) void combine_kernel(
    float* __restrict__ out, const u16* __restrict__ p_rt,
    const int* __restrict__ slot_of, const float* __restrict__ tok_w) {
  int tok = blockIdx.x;
  int j = threadIdx.x;               // 256 threads x 8 cols = 2048
  int s0 = slot_of[2 * tok], s1 = slot_of[2 * tok + 1];
  float w0 = tok_w[2 * tok], w1 = tok_w[2 * tok + 1];
  const u16* r0 = p_rt + (size_t)s0 * C_DIM + j * 8;
  const u16* r1 = p_rt + (size_t)s1 * C_DIM + j * 8;
  float* o = out + (size_t)tok * C_DIM + j * 8;
  union { uint4 v; u16 s[8]; } P0, P1;
  P0.v = *(const uint4*)r0;
  P1.v = *(const uint4*)r1;
  float4 o0 = *(const float4*)o;
  float4 o1 = *(const float4*)(o + 4);
  float r[8];
#pragma unroll
  for (int e = 0; e < 8; ++e) r[e] = w0 * bf2f(P0.s[e]) + w1 * bf2f(P1.s[e]);
  o0.x += r[0]; o0.y += r[1]; o0.z += r[2]; o0.w += r[3];
  o1.x += r[4]; o1.y += r[5]; o1.z += r[6]; o1.w += r[7];
  *(float4*)o = o0;
  *(float4*)(o + 4) = o1;
}

// ---------------- host launch ----------------
extern "C" void kernel_launch(void* const* d_in, const int* in_sizes, int n_in,
                              void* d_out, int out_size, void* d_ws, size_t ws_size,
                              hipStream_t stream) {
  const float* x   = (const float*)d_in[0];
  const float* gw  = (const float*)d_in[1];
  const float* gb  = (const float*)d_in[2];
  const float* sgw = (const float*)d_in[3];
  const float* sdw = (const float*)d_in[4];
  const float* upw = (const float*)d_in[5];
  const float* dww = (const float*)d_in[6];
  float* out = (float*)d_out;

  char* ws = (char*)d_ws;
  size_t off = 0;
  auto take = [&](size_t bytes) -> void* {
    size_t o = (off + 255) & ~(size_t)255;
    off = o + bytes;
    return (void*)(ws + o);
  };

  u16* x_bf   = (u16*)take((size_t)N_TOK * C_DIM * 2);
  u16* sgw_bf = (u16*)take((size_t)(2 * HS_DIM) * C_DIM * 2);
  u16* sdw_bf = (u16*)take((size_t)C_DIM * HS_DIM * 2);
  u16* upw_bf = (u16*)take((size_t)E_NUM * (2 * H_DIM) * C_DIM * 2);   // 92.3 MB
  u16* dww_bf = (u16*)take((size_t)E_NUM * C_DIM * H_DIM * 2);
  u16* h_sh   = (u16*)take((size_t)N_TOK * HS_DIM * 2);
  u16* h_rt   = (u16*)take((size_t)NRPAD * H_DIM * 2);                 // own buffer
  u16* p_rt   = upw_bf;  // alias: upw_bf dead after routed-up GEMM (75.5 <= 92.3 MB)

  int*   tok_e    = (int*)take((size_t)N_TOK * 2 * 4);
  float* tok_w    = (float*)take((size_t)N_TOK * 2 * 4);
  int*   slot_of  = (int*)take((size_t)N_TOK * 2 * 4);
  int*   slot_tok = (int*)take((size_t)NRPAD * 4);      // zeroed span start
  int*   counts   = (int*)take(E_NUM * 4);
  int*   cursor   = (int*)take(E_NUM * 4);
  int*   off_pad  = (int*)take(E_NUM * 4);
  int*   ntiles   = (int*)take(4);
  int*   tile_e   = (int*)take(MAXT256 * 4);
  int*   tile_s0  = (int*)take(MAXT256 * 4);
  (void)ws_size; (void)in_sizes; (void)n_in; (void)out_size;

  // zero slot_tok + counts + cursor (contiguous span)
  size_t z0 = (size_t)((char*)slot_tok - ws);
  size_t z1 = (size_t)((char*)cursor - ws) + E_NUM * 4;
  hipMemsetAsync(ws + z0, 0, z1 - z0, stream);

  // weight/activation bf16 conversion
  cvt_bf16_kernel<<<2048, 256, 0, stream>>>(x, x_bf, N_TOK * C_DIM / 4);
  cvt_bf16_kernel<<<2048, 256, 0, stream>>>(sgw, sgw_bf, 2 * HS_DIM * C_DIM / 4);
  cvt_bf16_kernel<<<2048, 256, 0, stream>>>(sdw, sdw_bf, C_DIM * HS_DIM / 4);
  cvt_bf16_kernel<<<4096, 256, 0, stream>>>(upw, upw_bf, E_NUM * 2 * H_DIM * C_DIM / 4);
  cvt_bf16_kernel<<<4096, 256, 0, stream>>>(dww, dww_bf, E_NUM * C_DIM * H_DIM / 4);

  gate_topk_kernel<<<N_TOK, 256, 0, stream>>>(x, gw, gb, tok_e, tok_w, counts);
  scan_route_kernel<<<1, 64, 0, stream>>>(counts, off_pad, tile_e, tile_s0, ntiles);
  build_slots_kernel<<<32, 256, 0, stream>>>(tok_e, off_pad, cursor, slot_tok, slot_of);

  // shared up (fused SwiGLU): h_sh = silu(x@g^T)*(x@y^T); sil rows [HS,2HS), mul [0,HS)
  // 32 mt x 22 nt(128-col h tiles) = 704 blocks
  gemm256<false, false, false, true><<<32 * 22, 512, 0, stream>>>(
      x_bf, sgw_bf, h_sh, HS_DIM, C_DIM, 22,
      nullptr, nullptr, nullptr, nullptr, 0, HS_DIM, 0);

  // routed up (fused SwiGLU): h_rt = silu(gather(x)@g^T)*(gather(x)@u^T)
  // sil rows [0,H), mul [H,2H); 72 mt x 11 nt = 792 blocks
  gemm256<true, true, false, true><<<MAXT256 * 11, 512, 0, stream>>>(
      x_bf, upw_bf, h_rt, H_DIM, C_DIM, 11,
      tile_e, tile_s0, ntiles, slot_tok, (long)(2 * H_DIM) * C_DIM, 0, H_DIM);

  // shared down: out = h_sh @ sdw^T (f32 store); 32 mt x 8 nt = 256 blocks
  gemm256<false, false, true, false><<<32 * 8, 512, 0, stream>>>(
      h_sh, sdw_bf, out, C_DIM, HS_DIM, 8,
      nullptr, nullptr, nullptr, nullptr, 0, 0, 0);

  // routed down: p_rt[slot] = h_rt[slot] @ dww[e]^T (bf16); 72 mt x 8 nt
  gemm256<false, true, false, false><<<MAXT256 * 8, 512, 0, stream>>>(
      h_rt, dww_bf, p_rt, C_DIM, H_DIM, 8,
      tile_e, tile_s0, ntiles, nullptr, (long)C_DIM * H_DIM, 0, 0);

  // combine: out[tok] += w0*p_rt[slot0] + w1*p_rt[slot1]
  combine_kernel<<<N_TOK, 256, 0, stream>>>(out, p_rt, slot_of, tok_w);
}